// Round 12
// baseline (203.609 us; speedup 1.0000x reference)
//
#include <hip/hip_runtime.h>
#include <hip/hip_fp16.h>
#include <math.h>

#define HIDC 96
#define HEADS 4
#define RMAX 40    // max relations staged in LDS (bench: R=38)
#define BINSZ 64   // dst nodes per bin (dlocal fits 6 bits)
#define BINB 6
#define BINCAP 1344 // words per bin region (Poisson 1024 + pad ~96: +6.8 sigma)
#define TILE 2048  // edges per bin_edges tile
#define SRCB 18    // src bits (N < 262144)
#define SRCM ((1 << SRCB) - 1)
#define ETB 6      // et bits (R < 64)
#define NBMAX 1024 // LDS histogram capacity (nbins = 782 at N=50K)

typedef unsigned u32x2 __attribute__((ext_vector_type(2)));

__device__ __forceinline__ __half2 u2h2(unsigned u) {
    return *reinterpret_cast<__half2*>(&u);
}
__device__ __forceinline__ unsigned h22u(__half2 h) {
    return *reinterpret_cast<unsigned*>(&h);
}

// ------------------------------------------------------------------
// h16 = half(x @ W); also zeroes bin counters + csr global tail.
__global__ __launch_bounds__(192) void gemm96(const float* __restrict__ x,
                                              const float* __restrict__ W,
                                              __half* __restrict__ h16,
                                              int* __restrict__ bincnt,
                                              int4* __restrict__ csrtail,
                                              int n, int nbins) {
    for (int i = blockIdx.x * 192 + threadIdx.x; i < nbins; i += gridDim.x * 192)
        bincnt[i] = 0;
    if (blockIdx.x == 0 && threadIdx.x < 16)
        csrtail[threadIdx.x] = make_int4(0, 0, 0, 0);   // slack past last bin

    __shared__ float Ws[HIDC * HIDC];
    __shared__ float xs[32 * HIDC];
    for (int i = threadIdx.x; i < HIDC * HIDC / 4; i += 192)
        reinterpret_cast<float4*>(Ws)[i] = reinterpret_cast<const float4*>(W)[i];
    int c4 = threadIdx.x % 24;
    int r0 = (threadIdx.x / 24) * 4;
    const float4* xs4 = reinterpret_cast<const float4*>(xs);
    const float4* Ws4 = reinterpret_cast<const float4*>(Ws);
    uint2* h8 = reinterpret_cast<uint2*>(h16);
    int numTiles = (n + 31) >> 5;
    for (int tile = blockIdx.x; tile < numTiles; tile += gridDim.x) {
        int row0 = tile << 5;
        int rows = min(32, n - row0);
        __syncthreads();
        for (int i = threadIdx.x; i < rows * 24; i += 192)
            reinterpret_cast<float4*>(xs)[i] =
                reinterpret_cast<const float4*>(x + (size_t)row0 * HIDC)[i];
        __syncthreads();
        float4 acc[4];
#pragma unroll
        for (int i = 0; i < 4; ++i) acc[i] = make_float4(0.f, 0.f, 0.f, 0.f);
#pragma unroll 4
        for (int k4 = 0; k4 < 24; ++k4) {
            float4 xv[4], wv[4];
#pragma unroll
            for (int i = 0; i < 4; ++i) xv[i] = xs4[(r0 + i) * 24 + k4];
#pragma unroll
            for (int j = 0; j < 4; ++j) wv[j] = Ws4[(k4 * 4 + j) * 24 + c4];
#pragma unroll
            for (int i = 0; i < 4; ++i) {
                const float xi[4] = {xv[i].x, xv[i].y, xv[i].z, xv[i].w};
#pragma unroll
                for (int j = 0; j < 4; ++j) {
                    acc[i].x = fmaf(xi[j], wv[j].x, acc[i].x);
                    acc[i].y = fmaf(xi[j], wv[j].y, acc[i].y);
                    acc[i].z = fmaf(xi[j], wv[j].z, acc[i].z);
                    acc[i].w = fmaf(xi[j], wv[j].w, acc[i].w);
                }
            }
        }
#pragma unroll
        for (int i = 0; i < 4; ++i)
            if (r0 + i < rows) {
                __half2 lo = __floats2half2_rn(acc[i].x, acc[i].y);
                __half2 hi = __floats2half2_rn(acc[i].z, acc[i].w);
                uint2 pk;
                pk.x = h22u(lo);
                pk.y = h22u(hi);
                h8[(size_t)(row0 + r0 + i) * 24 + c4] = pk;
            }
    }
}

// ------------------------------------------------------------------
// per-node attention scalars; last block computes per-relation scalars.
__global__ __launch_bounds__(256) void node_dots(
    const __half* __restrict__ h16,
    const float* __restrict__ att_src, const float* __restrict__ att_dst,
    const float* __restrict__ rel, const float* __restrict__ att_rel,
    float4* __restrict__ ps, float* __restrict__ pdi,
    float4* __restrict__ pr, int n, int R_) {
    if (blockIdx.x == gridDim.x - 1) {
        int t = threadIdx.x;
        if (t < R_) {
            const float4* rp = reinterpret_cast<const float4*>(rel + (size_t)t * HIDC);
            const float4* ar = reinterpret_cast<const float4*>(att_rel);
            float acc[HEADS] = {0, 0, 0, 0};
#pragma unroll
            for (int c = 0; c < 24; ++c) {
                float4 v = rp[c], a = ar[c];
                acc[c / 6] += v.x * a.x + v.y * a.y + v.z * a.z + v.w * a.w;
            }
            pr[t] = make_float4(acc[0], acc[1], acc[2], acc[3]);
        }
        return;
    }
    int i = blockIdx.x * blockDim.x + threadIdx.x;
    if (i >= n) return;
    const uint2* hp = reinterpret_cast<const uint2*>(h16 + (size_t)i * HIDC);
    const float4* as = reinterpret_cast<const float4*>(att_src);
    const float4* ad = reinterpret_cast<const float4*>(att_dst);
    float accs[HEADS] = {0, 0, 0, 0}, accd[HEADS] = {0, 0, 0, 0};
#pragma unroll
    for (int c = 0; c < 24; ++c) {
        uint2 hv = hp[c];
        float2 f0 = __half22float2(u2h2(hv.x));
        float2 f1 = __half22float2(u2h2(hv.y));
        float4 a = as[c], d = ad[c];
        int hh = c / 6;
        accs[hh] += f0.x * a.x + f0.y * a.y + f1.x * a.z + f1.y * a.w;
        accd[hh] += f0.x * d.x + f0.y * d.y + f1.x * d.z + f1.y * d.w;
    }
    ps[i] = make_float4(accs[0], accs[1], accs[2], accs[3]);
    *reinterpret_cast<float4*>(pdi + (size_t)i * 8) =
        make_float4(accd[0], accd[1], accd[2], accd[3]);
}

// ------------------------------------------------------------------
__device__ __forceinline__ float4 ev4(float4 a, float4 b, float4 c) {
    float l0 = a.x + b.x + c.x, l1 = a.y + b.y + c.y;
    float l2 = a.z + b.z + c.z, l3 = a.w + b.w + c.w;
    l0 = l0 >= 0.f ? l0 : 0.2f * l0;
    l1 = l1 >= 0.f ? l1 : 0.2f * l1;
    l2 = l2 >= 0.f ? l2 : 0.2f * l2;
    l3 = l3 >= 0.f ? l3 : 0.2f * l3;
    return make_float4(__expf(l0), __expf(l1), __expf(l2), __expf(l3));
}

__device__ __forceinline__ float gelu_f(float v) {
    float u = 0.7978845608028654f * (v + 0.044715f * v * v * v);
    u = fminf(fmaxf(u, -15.f), 15.f);
    float t = __expf(2.f * u);
    return 0.5f * v * (1.f + (t - 1.f) / (t + 1.f));
}

// ------------------------------------------------------------------
// Stage 1: bin edges by dst/64. LDS histogram gives per-tile local
// ranks; one global atomic per (tile,bin) reserves space.
__global__ __launch_bounds__(256) void bin_edges(
    const int* __restrict__ src, const int* __restrict__ dst,
    const int* __restrict__ et,
    int* __restrict__ bincnt, int* __restrict__ binwords,
    int E_, int nbins) {
    __shared__ int hist[NBMAX];
    __shared__ int base[NBMAX];
    int e0 = blockIdx.x * TILE;
    for (int i = threadIdx.x; i < nbins; i += 256) hist[i] = 0;
    __syncthreads();
    int mybin[8], myrank[8], myword[8];
#pragma unroll
    for (int u = 0; u < 8; ++u) {
        int e = e0 + u * 256 + threadIdx.x;
        mybin[u] = -1;
        if (e < E_) {
            int d = dst[e];
            int b = d >> BINB;
            myword[u] = src[e] | (et[e] << SRCB) | ((d & (BINSZ - 1)) << (SRCB + ETB));
            mybin[u] = b;
            myrank[u] = atomicAdd(&hist[b], 1);
        }
    }
    __syncthreads();
    for (int i = threadIdx.x; i < nbins; i += 256)
        base[i] = hist[i] > 0 ? atomicAdd(&bincnt[i], hist[i]) : 0;
    __syncthreads();
#pragma unroll
    for (int u = 0; u < 8; ++u) {
        if (mybin[u] >= 0) {
            int pos = base[mybin[u]] + myrank[u];
            if (pos < BINCAP)
                binwords[(size_t)mybin[u] * BINCAP + pos] = myword[u];
        }
    }
}

// ------------------------------------------------------------------
// Stage 2: one block per bin (782 blocks at N=50K — was 391 with
// BINSZ=128; low block count starved the chip). Counting-sort words by
// dlocal, compute ev, emit 16B CSR payload {src_byteoff, et_byteoff,
// ev01, ev23} + per-node noff/ncnt. Segments zero-padded to x4; 12
// zero entries past the bin total cover node_agg's 4-entry over-read.
__global__ __launch_bounds__(256) void bin_sort(
    const int* __restrict__ bincnt, const int* __restrict__ binwords,
    const float4* __restrict__ ps, const float* __restrict__ pdi,
    const float4* __restrict__ prg,
    int4* __restrict__ csr, int* __restrict__ noff, int* __restrict__ ncnt,
    int n, int R_) {
    __shared__ int cnts[BINSZ];
    __shared__ int scanb[BINSZ];
    __shared__ int nbase[BINSZ];
    __shared__ float4 pdl[BINSZ];
    __shared__ float4 prl[RMAX];
    int bin = blockIdx.x;
    int node0 = bin * BINSZ;
    int total = min(bincnt[bin], BINCAP);

    for (int i = threadIdx.x; i < BINSZ; i += 256) {
        cnts[i] = 0;
        int nd = node0 + i;
        pdl[i] = (nd < n) ? *reinterpret_cast<const float4*>(pdi + (size_t)nd * 8)
                          : make_float4(0.f, 0.f, 0.f, 0.f);
    }
    for (int i = threadIdx.x; i < R_; i += 256) prl[i] = prg[i];
    __syncthreads();

    // pass 1: load words, per-node rank via LDS atomic (6*256 >= BINCAP)
    int w[6], rk[6];
#pragma unroll
    for (int u = 0; u < 6; ++u) {
        int k = u * 256 + threadIdx.x;
        rk[u] = -1;
        if (k < total) {
            w[u] = binwords[(size_t)bin * BINCAP + k];
            int dl = (w[u] >> (SRCB + ETB)) & (BINSZ - 1);
            rk[u] = atomicAdd(&cnts[dl], 1);
        }
    }
    __syncthreads();

    // exclusive prefix over PADDED counts (round up to 4) -> nbase
    if (threadIdx.x < BINSZ) scanb[threadIdx.x] = (cnts[threadIdx.x] + 3) & ~3;
    __syncthreads();
    for (int s = 1; s < BINSZ; s <<= 1) {
        int v = 0;
        if (threadIdx.x < BINSZ && threadIdx.x >= s) v = scanb[threadIdx.x - s];
        __syncthreads();
        if (threadIdx.x < BINSZ) scanb[threadIdx.x] += v;
        __syncthreads();
    }
    if (threadIdx.x < BINSZ) {
        int cnt = cnts[threadIdx.x];
        int cntP = (cnt + 3) & ~3;
        int nb = scanb[threadIdx.x] - cntP;
        nbase[threadIdx.x] = nb;
        int nd = node0 + threadIdx.x;
        if (nd < n) {
            noff[nd] = bin * BINCAP + nb;
            ncnt[nd] = cnt;
        }
        // zero-fill pad entries (<=3 per node)
        int4 z = make_int4(0, 0, 0, 0);
        for (int i = cnt; i < cntP; ++i)
            csr[(size_t)bin * BINCAP + nb + i] = z;
    }
    // zero 12 entries past the bin's padded grand total (over-read window)
    {
        int gt = scanb[BINSZ - 1];
        if (threadIdx.x < 12) {
            int p = gt + threadIdx.x;
            if (p < BINCAP)
                csr[(size_t)bin * BINCAP + p] = make_int4(0, 0, 0, 0);
        }
    }
    __syncthreads();

    // pass 2: compute ev, write CSR payload sequentially per node
#pragma unroll
    for (int u = 0; u < 6; ++u) {
        if (rk[u] >= 0) {
            int s = w[u] & SRCM;
            int t = (w[u] >> SRCB) & ((1 << ETB) - 1);
            int dl = (w[u] >> (SRCB + ETB)) & (BINSZ - 1);
            float4 v = ev4(ps[s], pdl[dl], prl[t]);
            int4 pk;
            pk.x = s * (HIDC * 2);   // byte offset into h16 (row = 192 B)
            pk.y = t * (HIDC * 2);   // byte offset into relh (row = 192 B)
            pk.z = (int)h22u(__floats2half2_rn(v.x, v.y));
            pk.w = (int)h22u(__floats2half2_rn(v.z, v.w));
            csr[(size_t)bin * BINCAP + nbase[dl] + rk[u]] = pk;
        }
    }
}

// ------------------------------------------------------------------
// node_agg: the R3 form — best measured of six ILP variants (42.6 us;
// fence 50.2, same-step asm 43.2, cross-step asm 52.5, 2-node 45.8).
// Zero-padded segments (no clamps), fma_mix f16 ops, compiler-scheduled.
// Grid = (N+15)/16 so each 24-lane half-wave gets EXACTLY 2 nodes
// (was 3.05 avg with 31% quantization imbalance at grid=2048).
__global__ __launch_bounds__(256) void node_agg(
    const __half* __restrict__ h16, const float* __restrict__ rel,
    const int4* __restrict__ csr, const int* __restrict__ noff,
    const int* __restrict__ ncnt,
    float* __restrict__ pdi, const float* __restrict__ bias,
    float* __restrict__ out, int n, int R_) {
    __shared__ uint2 relh[RMAX * HIDC / 4];   // rel as fp16, 7.7 KB
    for (int i = threadIdx.x; i < R_ * 24; i += 256) {
        float4 v = reinterpret_cast<const float4*>(rel)[i];
        uint2 pk;
        pk.x = h22u(__floats2half2_rn(v.x, v.y));
        pk.y = h22u(__floats2half2_rn(v.z, v.w));
        relh[i] = pk;
    }
    __syncthreads();

    int lane = threadIdx.x & 31;
    if (lane >= 24) return;
    const int j = lane;
    const int j4 = 4 * j;
    const int hh = j / 6;
    const unsigned joff = (unsigned)(j << 3);   // byte offset within a 192 B row
    const float4 bv = *reinterpret_cast<const float4*>(bias + j4);
    const char* h16c = reinterpret_cast<const char*>(h16);
    const char* relc = reinterpret_cast<const char*>(relh);
    const unsigned esel = (unsigned)(2 * hh) | ((unsigned)(2 * hh + 1) << 8);

    int hw0 = (blockIdx.x * blockDim.x + threadIdx.x) >> 5;
    int nHW = (gridDim.x * blockDim.x) >> 5;

    for (int hw = hw0; hw < n; hw += nHW) {
        int cnt = ncnt[hw];
        const int4* sp = csr + noff[hw];
        float a0 = 0.f, a1 = 0.f, a2 = 0.f, a3 = 0.f;
        float dsum = 0.f;

        if (cnt > 0) {
            int cntP = (cnt + 3) & ~3;   // segment is zero-padded to this
            int4 pc[4];
#pragma unroll
            for (int u = 0; u < 4; ++u) pc[u] = sp[u];
            sp += 4;

            for (int k = 0; k < cntP; k += 4, sp += 4) {
                uint2 hv[4], rv[4];
#pragma unroll
                for (int u = 0; u < 4; ++u)
                    hv[u] = *reinterpret_cast<const uint2*>(
                        h16c + (unsigned)pc[u].x + joff);
#pragma unroll
                for (int u = 0; u < 4; ++u)
                    rv[u] = *reinterpret_cast<const uint2*>(
                        relc + (unsigned)pc[u].y + joff);
                int4 pn[4];
#pragma unroll
                for (int u = 0; u < 4; ++u) pn[u] = sp[u];
#pragma unroll
                for (int u = 0; u < 4; ++u) {
                    unsigned e32 = __builtin_amdgcn_perm(
                        (unsigned)pc[u].w, (unsigned)pc[u].z, esel);
                    dsum += __half2float(__low2half(u2h2(e32)));
                    unsigned s01 = h22u(__hadd2(u2h2(hv[u].x), u2h2(rv[u].x)));
                    unsigned s23 = h22u(__hadd2(u2h2(hv[u].y), u2h2(rv[u].y)));
                    asm("v_fma_mix_f32 %0, %1, %2, %0 op_sel:[0,0,0] op_sel_hi:[1,1,0]"
                        : "+v"(a0) : "v"(s01), "v"(e32));
                    asm("v_fma_mix_f32 %0, %1, %2, %0 op_sel:[1,0,0] op_sel_hi:[1,1,0]"
                        : "+v"(a1) : "v"(s01), "v"(e32));
                    asm("v_fma_mix_f32 %0, %1, %2, %0 op_sel:[0,0,0] op_sel_hi:[1,1,0]"
                        : "+v"(a2) : "v"(s23), "v"(e32));
                    asm("v_fma_mix_f32 %0, %1, %2, %0 op_sel:[1,0,0] op_sel_hi:[1,1,0]"
                        : "+v"(a3) : "v"(s23), "v"(e32));
                }
#pragma unroll
                for (int u = 0; u < 4; ++u) pc[u] = pn[u];
            }
        }
        float inv = dsum > 0.f ? 1.f / dsum : 0.f;
        if ((j % 6) == 0) pdi[(size_t)hw * 8 + 4 + hh] = inv;   // invden -> pdi[4:8)
        float4 o;
        o.x = gelu_f(a0 * inv + bv.x);
        o.y = gelu_f(a1 * inv + bv.y);
        o.z = gelu_f(a2 * inv + bv.z);
        o.w = gelu_f(a3 * inv + bv.w);
        *reinterpret_cast<float4*>(out + (size_t)hw * HIDC + j4) = o;
    }
}

// ------------------------------------------------------------------
// alpha in original edge order; pd+inv share one 32B record per dst node
__global__ void alpha_edge(const int* __restrict__ src, const int* __restrict__ dst,
                           const int* __restrict__ et,
                           const float4* __restrict__ ps, const float* __restrict__ pdi,
                           const float4* __restrict__ pr,
                           float4* __restrict__ alpha, int E_) {
    int e = blockIdx.x * blockDim.x + threadIdx.x;
    if (e >= E_) return;
    int d = dst[e];
    const float4* rec = reinterpret_cast<const float4*>(pdi + (size_t)d * 8);
    float4 b = rec[0];
    float4 iv = rec[1];
    float4 v = ev4(ps[src[e]], b, pr[et[e]]);
    alpha[e] = make_float4(v.x * iv.x, v.y * iv.y, v.z * iv.z, v.w * iv.w);
}

// ------------------------------------------------------------------
extern "C" void kernel_launch(void* const* d_in, const int* in_sizes, int n_in,
                              void* d_out, int out_size, void* d_ws, size_t ws_size,
                              hipStream_t stream) {
    const float* x       = (const float*)d_in[0];
    const int*   eidx    = (const int*)d_in[1];
    const int*   etype   = (const int*)d_in[2];
    const float* W       = (const float*)d_in[3];
    const float* rel     = (const float*)d_in[4];
    const float* att_src = (const float*)d_in[5];
    const float* att_dst = (const float*)d_in[6];
    const float* att_rel = (const float*)d_in[7];
    const float* bias    = (const float*)d_in[8];

    int N_ = in_sizes[0] / HIDC;
    int E_ = in_sizes[1] / 2;
    int R_ = in_sizes[4] / HIDC;
    const int* src  = eidx;
    const int* dstp = eidx + E_;
    int nbins = (N_ + BINSZ - 1) / BINSZ;

    // workspace layout (16B-aligned chunks), ~33.5 MB total
    char* ws = (char*)d_ws;
    __half* h16      = (__half*)ws; ws += (size_t)N_ * HIDC * 2;        // 9.6 MB
    float4* ps       = (float4*)ws; ws += (size_t)N_ * 16;              // 0.8 MB
    float*  pdi      = (float*)ws;  ws += (size_t)N_ * 32;              // 1.6 MB (pd | inv)
    float4* pr       = (float4*)ws; ws += 1024;
    int*    bincnt   = (int*)ws;    ws += (size_t)((nbins + 3) & ~3) * 4;
    int*    noff     = (int*)ws;    ws += (size_t)((N_ + 3) & ~3) * 4;  // 0.2 MB
    int*    ncnt     = (int*)ws;    ws += (size_t)((N_ + 3) & ~3) * 4;  // 0.2 MB
    int*    binwords = (int*)ws;    ws += (size_t)nbins * BINCAP * 4;   // 4.2 MB
    int4*   csr      = (int4*)ws;   ws += (size_t)nbins * BINCAP * 16 + 256; // 16.8 MB (+slack)

    float*  outv  = (float*)d_out;                       // N*96
    float4* alpha = (float4*)(outv + (size_t)N_ * HIDC); // E*4

    gemm96<<<(N_ + 31) / 32, 192, 0, stream>>>(
        x, W, h16, bincnt, csr + (size_t)nbins * BINCAP, N_, nbins);

    node_dots<<<(N_ + 255) / 256 + 1, 256, 0, stream>>>(
        h16, att_src, att_dst, rel, att_rel, ps, pdi, pr, N_, R_);

    bin_edges<<<(E_ + TILE - 1) / TILE, 256, 0, stream>>>(
        src, dstp, etype, bincnt, binwords, E_, nbins);

    bin_sort<<<nbins, 256, 0, stream>>>(
        bincnt, binwords, ps, pdi, pr, csr, noff, ncnt, N_, R_);

    node_agg<<<(N_ + 15) / 16, 256, 0, stream>>>(
        h16, rel, csr, noff, ncnt, pdi, bias, outv, N_, R_);

    alpha_edge<<<(E_ + 255) / 256, 256, 0, stream>>>(
        src, dstp, etype, ps, pdi, pr, alpha, E_);
}

// Round 13
// 192.643 us; speedup vs baseline: 1.0569x; 1.0569x over previous
//
#include <hip/hip_runtime.h>
#include <hip/hip_fp16.h>
#include <math.h>

#define HIDC 96
#define HEADS 4
#define RMAX 40    // max relations staged in LDS (bench: R=38)
#define BINSZ 64   // dst nodes per bin (dlocal fits 6 bits)
#define BINB 6
#define BINCAP 1344 // words per bin region (Poisson 1024 + pad ~96: +6.8 sigma)
#define TILE 2048  // edges per bin_edges tile
#define SRCB 18    // src bits (N < 262144)
#define SRCM ((1 << SRCB) - 1)
#define ETB 6      // et bits (R < 64)
#define NBMAX 1024 // LDS histogram capacity (nbins = 782 at N=50K)

typedef unsigned u32x2 __attribute__((ext_vector_type(2)));

__device__ __forceinline__ __half2 u2h2(unsigned u) {
    return *reinterpret_cast<__half2*>(&u);
}
__device__ __forceinline__ unsigned h22u(__half2 h) {
    return *reinterpret_cast<unsigned*>(&h);
}

// ------------------------------------------------------------------
// h16 = half(x @ W); also zeroes bin counters + csr global tail.
__global__ __launch_bounds__(192) void gemm96(const float* __restrict__ x,
                                              const float* __restrict__ W,
                                              __half* __restrict__ h16,
                                              int* __restrict__ bincnt,
                                              int4* __restrict__ csrtail,
                                              int n, int nbins) {
    for (int i = blockIdx.x * 192 + threadIdx.x; i < nbins; i += gridDim.x * 192)
        bincnt[i] = 0;
    if (blockIdx.x == 0 && threadIdx.x < 16)
        csrtail[threadIdx.x] = make_int4(0, 0, 0, 0);   // slack past last bin

    __shared__ float Ws[HIDC * HIDC];
    __shared__ float xs[32 * HIDC];
    for (int i = threadIdx.x; i < HIDC * HIDC / 4; i += 192)
        reinterpret_cast<float4*>(Ws)[i] = reinterpret_cast<const float4*>(W)[i];
    int c4 = threadIdx.x % 24;
    int r0 = (threadIdx.x / 24) * 4;
    const float4* xs4 = reinterpret_cast<const float4*>(xs);
    const float4* Ws4 = reinterpret_cast<const float4*>(Ws);
    uint2* h8 = reinterpret_cast<uint2*>(h16);
    int numTiles = (n + 31) >> 5;
    for (int tile = blockIdx.x; tile < numTiles; tile += gridDim.x) {
        int row0 = tile << 5;
        int rows = min(32, n - row0);
        __syncthreads();
        for (int i = threadIdx.x; i < rows * 24; i += 192)
            reinterpret_cast<float4*>(xs)[i] =
                reinterpret_cast<const float4*>(x + (size_t)row0 * HIDC)[i];
        __syncthreads();
        float4 acc[4];
#pragma unroll
        for (int i = 0; i < 4; ++i) acc[i] = make_float4(0.f, 0.f, 0.f, 0.f);
#pragma unroll 4
        for (int k4 = 0; k4 < 24; ++k4) {
            float4 xv[4], wv[4];
#pragma unroll
            for (int i = 0; i < 4; ++i) xv[i] = xs4[(r0 + i) * 24 + k4];
#pragma unroll
            for (int j = 0; j < 4; ++j) wv[j] = Ws4[(k4 * 4 + j) * 24 + c4];
#pragma unroll
            for (int i = 0; i < 4; ++i) {
                const float xi[4] = {xv[i].x, xv[i].y, xv[i].z, xv[i].w};
#pragma unroll
                for (int j = 0; j < 4; ++j) {
                    acc[i].x = fmaf(xi[j], wv[j].x, acc[i].x);
                    acc[i].y = fmaf(xi[j], wv[j].y, acc[i].y);
                    acc[i].z = fmaf(xi[j], wv[j].z, acc[i].z);
                    acc[i].w = fmaf(xi[j], wv[j].w, acc[i].w);
                }
            }
        }
#pragma unroll
        for (int i = 0; i < 4; ++i)
            if (r0 + i < rows) {
                __half2 lo = __floats2half2_rn(acc[i].x, acc[i].y);
                __half2 hi = __floats2half2_rn(acc[i].z, acc[i].w);
                uint2 pk;
                pk.x = h22u(lo);
                pk.y = h22u(hi);
                h8[(size_t)(row0 + r0 + i) * 24 + c4] = pk;
            }
    }
}

// ------------------------------------------------------------------
// per-node attention scalars; last block computes per-relation scalars.
__global__ __launch_bounds__(256) void node_dots(
    const __half* __restrict__ h16,
    const float* __restrict__ att_src, const float* __restrict__ att_dst,
    const float* __restrict__ rel, const float* __restrict__ att_rel,
    float4* __restrict__ ps, float* __restrict__ pdi,
    float4* __restrict__ pr, int n, int R_) {
    if (blockIdx.x == gridDim.x - 1) {
        int t = threadIdx.x;
        if (t < R_) {
            const float4* rp = reinterpret_cast<const float4*>(rel + (size_t)t * HIDC);
            const float4* ar = reinterpret_cast<const float4*>(att_rel);
            float acc[HEADS] = {0, 0, 0, 0};
#pragma unroll
            for (int c = 0; c < 24; ++c) {
                float4 v = rp[c], a = ar[c];
                acc[c / 6] += v.x * a.x + v.y * a.y + v.z * a.z + v.w * a.w;
            }
            pr[t] = make_float4(acc[0], acc[1], acc[2], acc[3]);
        }
        return;
    }
    int i = blockIdx.x * blockDim.x + threadIdx.x;
    if (i >= n) return;
    const uint2* hp = reinterpret_cast<const uint2*>(h16 + (size_t)i * HIDC);
    const float4* as = reinterpret_cast<const float4*>(att_src);
    const float4* ad = reinterpret_cast<const float4*>(att_dst);
    float accs[HEADS] = {0, 0, 0, 0}, accd[HEADS] = {0, 0, 0, 0};
#pragma unroll
    for (int c = 0; c < 24; ++c) {
        uint2 hv = hp[c];
        float2 f0 = __half22float2(u2h2(hv.x));
        float2 f1 = __half22float2(u2h2(hv.y));
        float4 a = as[c], d = ad[c];
        int hh = c / 6;
        accs[hh] += f0.x * a.x + f0.y * a.y + f1.x * a.z + f1.y * a.w;
        accd[hh] += f0.x * d.x + f0.y * d.y + f1.x * d.z + f1.y * d.w;
    }
    ps[i] = make_float4(accs[0], accs[1], accs[2], accs[3]);
    *reinterpret_cast<float4*>(pdi + (size_t)i * 8) =
        make_float4(accd[0], accd[1], accd[2], accd[3]);
}

// ------------------------------------------------------------------
__device__ __forceinline__ float4 ev4(float4 a, float4 b, float4 c) {
    float l0 = a.x + b.x + c.x, l1 = a.y + b.y + c.y;
    float l2 = a.z + b.z + c.z, l3 = a.w + b.w + c.w;
    l0 = l0 >= 0.f ? l0 : 0.2f * l0;
    l1 = l1 >= 0.f ? l1 : 0.2f * l1;
    l2 = l2 >= 0.f ? l2 : 0.2f * l2;
    l3 = l3 >= 0.f ? l3 : 0.2f * l3;
    return make_float4(__expf(l0), __expf(l1), __expf(l2), __expf(l3));
}

__device__ __forceinline__ float gelu_f(float v) {
    float u = 0.7978845608028654f * (v + 0.044715f * v * v * v);
    u = fminf(fmaxf(u, -15.f), 15.f);
    float t = __expf(2.f * u);
    return 0.5f * v * (1.f + (t - 1.f) / (t + 1.f));
}

// ------------------------------------------------------------------
// Stage 1: bin edges by dst/64. Each record carries {packed word, edge
// id} so alpha can be produced from the CSR side (alpha_edge deleted).
__global__ __launch_bounds__(256) void bin_edges(
    const int* __restrict__ src, const int* __restrict__ dst,
    const int* __restrict__ et,
    int* __restrict__ bincnt, int2* __restrict__ binwords,
    int E_, int nbins) {
    __shared__ int hist[NBMAX];
    __shared__ int base[NBMAX];
    int e0 = blockIdx.x * TILE;
    for (int i = threadIdx.x; i < nbins; i += 256) hist[i] = 0;
    __syncthreads();
    int mybin[8], myrank[8], myword[8];
#pragma unroll
    for (int u = 0; u < 8; ++u) {
        int e = e0 + u * 256 + threadIdx.x;
        mybin[u] = -1;
        if (e < E_) {
            int d = dst[e];
            int b = d >> BINB;
            myword[u] = src[e] | (et[e] << SRCB) | ((d & (BINSZ - 1)) << (SRCB + ETB));
            mybin[u] = b;
            myrank[u] = atomicAdd(&hist[b], 1);
        }
    }
    __syncthreads();
    for (int i = threadIdx.x; i < nbins; i += 256)
        base[i] = hist[i] > 0 ? atomicAdd(&bincnt[i], hist[i]) : 0;
    __syncthreads();
#pragma unroll
    for (int u = 0; u < 8; ++u) {
        if (mybin[u] >= 0) {
            int pos = base[mybin[u]] + myrank[u];
            if (pos < BINCAP)
                binwords[(size_t)mybin[u] * BINCAP + pos] =
                    make_int2(myword[u], e0 + u * 256 + threadIdx.x);
        }
    }
}

// ------------------------------------------------------------------
// Stage 2: one block per bin. Counting-sort by dlocal, compute ev, emit
// 16B CSR payload. Edge id (20b) is packed into spare bits:
//   pk.x = src_byteoff(24b) | e[7:0]<<24
//   pk.y = et_byteoff(13b)  | e[19:8]<<13
// Segments zero-padded to x4 (pads: all-zero; safe masked offsets, ev=0,
// never alpha-written since pass-2 bounds by exact cnt).
__global__ __launch_bounds__(256) void bin_sort(
    const int* __restrict__ bincnt, const int2* __restrict__ binwords,
    const float4* __restrict__ ps, const float* __restrict__ pdi,
    const float4* __restrict__ prg,
    int4* __restrict__ csr, int* __restrict__ noff, int* __restrict__ ncnt,
    int n, int R_) {
    __shared__ int cnts[BINSZ];
    __shared__ int scanb[BINSZ];
    __shared__ int nbase[BINSZ];
    __shared__ float4 pdl[BINSZ];
    __shared__ float4 prl[RMAX];
    int bin = blockIdx.x;
    int node0 = bin * BINSZ;
    int total = min(bincnt[bin], BINCAP);

    for (int i = threadIdx.x; i < BINSZ; i += 256) {
        cnts[i] = 0;
        int nd = node0 + i;
        pdl[i] = (nd < n) ? *reinterpret_cast<const float4*>(pdi + (size_t)nd * 8)
                          : make_float4(0.f, 0.f, 0.f, 0.f);
    }
    for (int i = threadIdx.x; i < R_; i += 256) prl[i] = prg[i];
    __syncthreads();

    // pass 1: load records, per-node rank via LDS atomic (6*256 >= BINCAP)
    int2 w[6];
    int rk[6];
#pragma unroll
    for (int u = 0; u < 6; ++u) {
        int k = u * 256 + threadIdx.x;
        rk[u] = -1;
        if (k < total) {
            w[u] = binwords[(size_t)bin * BINCAP + k];
            int dl = (w[u].x >> (SRCB + ETB)) & (BINSZ - 1);
            rk[u] = atomicAdd(&cnts[dl], 1);
        }
    }
    __syncthreads();

    // exclusive prefix over PADDED counts (round up to 4) -> nbase
    if (threadIdx.x < BINSZ) scanb[threadIdx.x] = (cnts[threadIdx.x] + 3) & ~3;
    __syncthreads();
    for (int s = 1; s < BINSZ; s <<= 1) {
        int v = 0;
        if (threadIdx.x < BINSZ && threadIdx.x >= s) v = scanb[threadIdx.x - s];
        __syncthreads();
        if (threadIdx.x < BINSZ) scanb[threadIdx.x] += v;
        __syncthreads();
    }
    if (threadIdx.x < BINSZ) {
        int cnt = cnts[threadIdx.x];
        int cntP = (cnt + 3) & ~3;
        int nb = scanb[threadIdx.x] - cntP;
        nbase[threadIdx.x] = nb;
        int nd = node0 + threadIdx.x;
        if (nd < n) {
            noff[nd] = bin * BINCAP + nb;
            ncnt[nd] = cnt;
        }
        // zero-fill pad entries (<=3 per node)
        int4 z = make_int4(0, 0, 0, 0);
        for (int i = cnt; i < cntP; ++i)
            csr[(size_t)bin * BINCAP + nb + i] = z;
    }
    // zero 12 entries past the bin's padded grand total (over-read window)
    {
        int gt = scanb[BINSZ - 1];
        if (threadIdx.x < 12) {
            int p = gt + threadIdx.x;
            if (p < BINCAP)
                csr[(size_t)bin * BINCAP + p] = make_int4(0, 0, 0, 0);
        }
    }
    __syncthreads();

    // pass 2: compute ev, write CSR payload sequentially per node
#pragma unroll
    for (int u = 0; u < 6; ++u) {
        if (rk[u] >= 0) {
            int s = w[u].x & SRCM;
            int t = (w[u].x >> SRCB) & ((1 << ETB) - 1);
            int dl = (w[u].x >> (SRCB + ETB)) & (BINSZ - 1);
            unsigned e = (unsigned)w[u].y;   // < 2^20
            float4 v = ev4(ps[s], pdl[dl], prl[t]);
            int4 pk;
            pk.x = (int)((unsigned)(s * (HIDC * 2)) | ((e & 0xFFu) << 24));
            pk.y = (int)((unsigned)(t * (HIDC * 2)) | ((e >> 8) << 13));
            pk.z = (int)h22u(__floats2half2_rn(v.x, v.y));
            pk.w = (int)h22u(__floats2half2_rn(v.z, v.w));
            csr[(size_t)bin * BINCAP + nbase[dl] + rk[u]] = pk;
        }
    }
}

// ------------------------------------------------------------------
// node_agg + fused alpha: R3-form main loop (best of seven variants),
// then a second pass over the node's CSR segment writes
// alpha[e] = ev * inv using the packed edge id — alpha_edge kernel and
// its 3-random-gathers-per-edge are deleted entirely.
__global__ __launch_bounds__(256) void node_agg(
    const __half* __restrict__ h16, const float* __restrict__ rel,
    const int4* __restrict__ csr, const int* __restrict__ noff,
    const int* __restrict__ ncnt,
    const float* __restrict__ bias,
    float* __restrict__ out, float4* __restrict__ alpha, int n, int R_) {
    __shared__ uint2 relh[RMAX * HIDC / 4];   // rel as fp16, 7.7 KB
    for (int i = threadIdx.x; i < R_ * 24; i += 256) {
        float4 v = reinterpret_cast<const float4*>(rel)[i];
        uint2 pk;
        pk.x = h22u(__floats2half2_rn(v.x, v.y));
        pk.y = h22u(__floats2half2_rn(v.z, v.w));
        relh[i] = pk;
    }
    __syncthreads();

    int lane = threadIdx.x & 31;
    if (lane >= 24) return;
    const int j = lane;
    const int j4 = 4 * j;
    const int hh = j / 6;
    const unsigned joff = (unsigned)(j << 3);   // byte offset within a 192 B row
    const float4 bv = *reinterpret_cast<const float4*>(bias + j4);
    const char* h16c = reinterpret_cast<const char*>(h16);
    const char* relc = reinterpret_cast<const char*>(relh);
    const unsigned esel = (unsigned)(2 * hh) | ((unsigned)(2 * hh + 1) << 8);

    int hw0 = (blockIdx.x * blockDim.x + threadIdx.x) >> 5;
    int nHW = (gridDim.x * blockDim.x) >> 5;

    for (int hw = hw0; hw < n; hw += nHW) {
        int cnt = ncnt[hw];
        const int4* sp0 = csr + noff[hw];
        const int4* sp = sp0;
        float a0 = 0.f, a1 = 0.f, a2 = 0.f, a3 = 0.f;
        float dsum = 0.f;

        if (cnt > 0) {
            int cntP = (cnt + 3) & ~3;   // segment is zero-padded to this
            int4 pc[4];
#pragma unroll
            for (int u = 0; u < 4; ++u) pc[u] = sp[u];
            sp += 4;

            for (int k = 0; k < cntP; k += 4, sp += 4) {
                uint2 hv[4], rv[4];
#pragma unroll
                for (int u = 0; u < 4; ++u)
                    hv[u] = *reinterpret_cast<const uint2*>(
                        h16c + ((unsigned)pc[u].x & 0x00FFFFFFu) + joff);
#pragma unroll
                for (int u = 0; u < 4; ++u)
                    rv[u] = *reinterpret_cast<const uint2*>(
                        relc + ((unsigned)pc[u].y & 0x1FFFu) + joff);
                int4 pn[4];
#pragma unroll
                for (int u = 0; u < 4; ++u) pn[u] = sp[u];
#pragma unroll
                for (int u = 0; u < 4; ++u) {
                    unsigned e32 = __builtin_amdgcn_perm(
                        (unsigned)pc[u].w, (unsigned)pc[u].z, esel);
                    dsum += __half2float(__low2half(u2h2(e32)));
                    unsigned s01 = h22u(__hadd2(u2h2(hv[u].x), u2h2(rv[u].x)));
                    unsigned s23 = h22u(__hadd2(u2h2(hv[u].y), u2h2(rv[u].y)));
                    asm("v_fma_mix_f32 %0, %1, %2, %0 op_sel:[0,0,0] op_sel_hi:[1,1,0]"
                        : "+v"(a0) : "v"(s01), "v"(e32));
                    asm("v_fma_mix_f32 %0, %1, %2, %0 op_sel:[1,0,0] op_sel_hi:[1,1,0]"
                        : "+v"(a1) : "v"(s01), "v"(e32));
                    asm("v_fma_mix_f32 %0, %1, %2, %0 op_sel:[0,0,0] op_sel_hi:[1,1,0]"
                        : "+v"(a2) : "v"(s23), "v"(e32));
                    asm("v_fma_mix_f32 %0, %1, %2, %0 op_sel:[1,0,0] op_sel_hi:[1,1,0]"
                        : "+v"(a3) : "v"(s23), "v"(e32));
                }
#pragma unroll
                for (int u = 0; u < 4; ++u) pc[u] = pn[u];
            }
        }
        float inv = dsum > 0.f ? 1.f / dsum : 0.f;
        float4 o;
        o.x = gelu_f(a0 * inv + bv.x);
        o.y = gelu_f(a1 * inv + bv.y);
        o.z = gelu_f(a2 * inv + bv.z);
        o.w = gelu_f(a3 * inv + bv.w);
        *reinterpret_cast<float4*>(out + (size_t)hw * HIDC + j4) = o;

        // fused alpha: inv for all 4 heads via intra-half shuffles, then
        // each lane handles edges j, j+24, ... (exact cnt bound: pads and
        // over-read window never produce writes).
        if (cnt > 0) {
            float iv0 = __shfl(inv, 0, 32);
            float iv1 = __shfl(inv, 6, 32);
            float iv2 = __shfl(inv, 12, 32);
            float iv3 = __shfl(inv, 18, 32);
            for (int k = j; k < cnt; k += 24) {
                int4 pk = sp0[k];
                unsigned e_id = ((unsigned)pk.x >> 24) | (((unsigned)pk.y >> 13) << 8);
                float2 f01 = __half22float2(u2h2((unsigned)pk.z));
                float2 f23 = __half22float2(u2h2((unsigned)pk.w));
                alpha[e_id] = make_float4(f01.x * iv0, f01.y * iv1,
                                          f23.x * iv2, f23.y * iv3);
            }
        }
    }
}

// ------------------------------------------------------------------
extern "C" void kernel_launch(void* const* d_in, const int* in_sizes, int n_in,
                              void* d_out, int out_size, void* d_ws, size_t ws_size,
                              hipStream_t stream) {
    const float* x       = (const float*)d_in[0];
    const int*   eidx    = (const int*)d_in[1];
    const int*   etype   = (const int*)d_in[2];
    const float* W       = (const float*)d_in[3];
    const float* rel     = (const float*)d_in[4];
    const float* att_src = (const float*)d_in[5];
    const float* att_dst = (const float*)d_in[6];
    const float* att_rel = (const float*)d_in[7];
    const float* bias    = (const float*)d_in[8];

    int N_ = in_sizes[0] / HIDC;
    int E_ = in_sizes[1] / 2;
    int R_ = in_sizes[4] / HIDC;
    const int* src  = eidx;
    const int* dstp = eidx + E_;
    int nbins = (N_ + BINSZ - 1) / BINSZ;

    // workspace layout (16B-aligned chunks), ~38 MB total
    char* ws = (char*)d_ws;
    __half* h16      = (__half*)ws; ws += (size_t)N_ * HIDC * 2;        // 9.6 MB
    float4* ps       = (float4*)ws; ws += (size_t)N_ * 16;              // 0.8 MB
    float*  pdi      = (float*)ws;  ws += (size_t)N_ * 32;              // 1.6 MB (pd | spare)
    float4* pr       = (float4*)ws; ws += 1024;
    int*    bincnt   = (int*)ws;    ws += (size_t)((nbins + 3) & ~3) * 4;
    int*    noff     = (int*)ws;    ws += (size_t)((N_ + 3) & ~3) * 4;  // 0.2 MB
    int*    ncnt     = (int*)ws;    ws += (size_t)((N_ + 3) & ~3) * 4;  // 0.2 MB
    int2*   binwords = (int2*)ws;   ws += (size_t)nbins * BINCAP * 8;   // 8.4 MB
    int4*   csr      = (int4*)ws;   ws += (size_t)nbins * BINCAP * 16 + 256; // 16.8 MB (+slack)

    float*  outv  = (float*)d_out;                       // N*96
    float4* alpha = (float4*)(outv + (size_t)N_ * HIDC); // E*4

    gemm96<<<(N_ + 31) / 32, 192, 0, stream>>>(
        x, W, h16, bincnt, csr + (size_t)nbins * BINCAP, N_, nbins);

    node_dots<<<(N_ + 255) / 256 + 1, 256, 0, stream>>>(
        h16, att_src, att_dst, rel, att_rel, ps, pdi, pr, N_, R_);

    bin_edges<<<(E_ + TILE - 1) / TILE, 256, 0, stream>>>(
        src, dstp, etype, bincnt, binwords, E_, nbins);

    bin_sort<<<nbins, 256, 0, stream>>>(
        bincnt, binwords, ps, pdi, pr, csr, noff, ncnt, N_, R_);

    node_agg<<<(N_ + 15) / 16, 256, 0, stream>>>(
        h16, rel, csr, noff, ncnt, bias, outv, alpha, N_, R_);
}

// Round 14
// 177.359 us; speedup vs baseline: 1.1480x; 1.0862x over previous
//
#include <hip/hip_runtime.h>
#include <hip/hip_fp16.h>
#include <math.h>

#define HIDC 96
#define HEADS 4
#define RMAX 40    // max relations staged in LDS (bench: R=38)
#define BINSZ 64   // dst nodes per bin (dlocal fits 6 bits)
#define BINB 6
#define BINCAP 1344 // words per bin region (Poisson 1024 + pad ~96: +6.8 sigma)
#define TILE 2048  // edges per bin_edges tile
#define SRCB 18    // src bits (N < 262144)
#define SRCM ((1 << SRCB) - 1)
#define ETB 6      // et bits (R < 64)
#define NBMAX 1024 // LDS histogram capacity (nbins = 782 at N=50K)

typedef unsigned u32x2 __attribute__((ext_vector_type(2)));
typedef _Float16 f16x4 __attribute__((ext_vector_type(4)));
typedef float f32x4 __attribute__((ext_vector_type(4)));

__device__ __forceinline__ __half2 u2h2(unsigned u) {
    return *reinterpret_cast<__half2*>(&u);
}
__device__ __forceinline__ unsigned h22u(__half2 h) {
    return *reinterpret_cast<unsigned*>(&h);
}

// ------------------------------------------------------------------
// h16 = half(x @ W) via MFMA f16 (fp32 vector GEMM was Common-mistake
// #10; MFMA makes this memory-bound). Layout (documented + HW-verified
// C/D): A lane l: i=l&15, k=4*(l>>4)+j;  B: j-col=l&15, same k;
// C/D: col=l&15, row=(l>>4)*4+reg. W staged once into 72 VGPRs of
// B-fragments. Also zeroes bin counters + csr global tail.
__global__ __launch_bounds__(256) void gemm96(const float* __restrict__ x,
                                              const float* __restrict__ W,
                                              __half* __restrict__ h16,
                                              int* __restrict__ bincnt,
                                              int4* __restrict__ csrtail,
                                              int n, int nbins) {
    for (int i = blockIdx.x * 256 + threadIdx.x; i < nbins; i += gridDim.x * 256)
        bincnt[i] = 0;
    if (blockIdx.x == 0 && threadIdx.x < 16)
        csrtail[threadIdx.x] = make_int4(0, 0, 0, 0);   // slack past last bin

    const int lane = threadIdx.x & 63;
    const int wave = threadIdx.x >> 6;
    const int lo16 = lane & 15;
    const int grp = lane >> 4;          // 0..3

    // B fragments: bf[kf][nt], lane holds W[kf*16+4*grp+j][nt*16+lo16]
    f16x4 bf[6][6];
#pragma unroll
    for (int kf = 0; kf < 6; ++kf)
#pragma unroll
        for (int nt = 0; nt < 6; ++nt) {
            f16x4 b;
#pragma unroll
            for (int j = 0; j < 4; ++j)
                b[j] = (_Float16)W[(kf * 16 + grp * 4 + j) * HIDC + nt * 16 + lo16];
            bf[kf][nt] = b;
        }

    int row0 = blockIdx.x * 64 + wave * 16;
    if (row0 >= n) return;
    int r = row0 + lo16;
    const float4* xr = reinterpret_cast<const float4*>(
        x + (size_t)min(r, n - 1) * HIDC);

    f32x4 c[6];
#pragma unroll
    for (int nt = 0; nt < 6; ++nt) c[nt] = (f32x4){0.f, 0.f, 0.f, 0.f};

#pragma unroll
    for (int kf = 0; kf < 6; ++kf) {
        float4 av = xr[kf * 4 + grp];   // cols 16*kf + 4*grp .. +3
        f16x4 af;
        af[0] = (_Float16)av.x; af[1] = (_Float16)av.y;
        af[2] = (_Float16)av.z; af[3] = (_Float16)av.w;
#pragma unroll
        for (int nt = 0; nt < 6; ++nt)
            c[nt] = __builtin_amdgcn_mfma_f32_16x16x16f16(af, bf[kf][nt], c[nt], 0, 0, 0);
    }

#pragma unroll
    for (int nt = 0; nt < 6; ++nt)
#pragma unroll
        for (int i = 0; i < 4; ++i) {
            int rr = row0 + grp * 4 + i;
            if (rr < n)
                h16[(size_t)rr * HIDC + nt * 16 + lo16] = (__half)c[nt][i];
        }
}

// ------------------------------------------------------------------
// per-node attention scalars; last block computes per-relation scalars.
__global__ __launch_bounds__(256) void node_dots(
    const __half* __restrict__ h16,
    const float* __restrict__ att_src, const float* __restrict__ att_dst,
    const float* __restrict__ rel, const float* __restrict__ att_rel,
    float4* __restrict__ ps, float* __restrict__ pdi,
    float4* __restrict__ pr, int n, int R_) {
    if (blockIdx.x == gridDim.x - 1) {
        int t = threadIdx.x;
        if (t < R_) {
            const float4* rp = reinterpret_cast<const float4*>(rel + (size_t)t * HIDC);
            const float4* ar = reinterpret_cast<const float4*>(att_rel);
            float acc[HEADS] = {0, 0, 0, 0};
#pragma unroll
            for (int c = 0; c < 24; ++c) {
                float4 v = rp[c], a = ar[c];
                acc[c / 6] += v.x * a.x + v.y * a.y + v.z * a.z + v.w * a.w;
            }
            pr[t] = make_float4(acc[0], acc[1], acc[2], acc[3]);
        }
        return;
    }
    int i = blockIdx.x * blockDim.x + threadIdx.x;
    if (i >= n) return;
    const uint2* hp = reinterpret_cast<const uint2*>(h16 + (size_t)i * HIDC);
    const float4* as = reinterpret_cast<const float4*>(att_src);
    const float4* ad = reinterpret_cast<const float4*>(att_dst);
    float accs[HEADS] = {0, 0, 0, 0}, accd[HEADS] = {0, 0, 0, 0};
#pragma unroll
    for (int c = 0; c < 24; ++c) {
        uint2 hv = hp[c];
        float2 f0 = __half22float2(u2h2(hv.x));
        float2 f1 = __half22float2(u2h2(hv.y));
        float4 a = as[c], d = ad[c];
        int hh = c / 6;
        accs[hh] += f0.x * a.x + f0.y * a.y + f1.x * a.z + f1.y * a.w;
        accd[hh] += f0.x * d.x + f0.y * d.y + f1.x * d.z + f1.y * d.w;
    }
    ps[i] = make_float4(accs[0], accs[1], accs[2], accs[3]);
    *reinterpret_cast<float4*>(pdi + (size_t)i * 8) =
        make_float4(accd[0], accd[1], accd[2], accd[3]);
}

// ------------------------------------------------------------------
__device__ __forceinline__ float4 ev4(float4 a, float4 b, float4 c) {
    float l0 = a.x + b.x + c.x, l1 = a.y + b.y + c.y;
    float l2 = a.z + b.z + c.z, l3 = a.w + b.w + c.w;
    l0 = l0 >= 0.f ? l0 : 0.2f * l0;
    l1 = l1 >= 0.f ? l1 : 0.2f * l1;
    l2 = l2 >= 0.f ? l2 : 0.2f * l2;
    l3 = l3 >= 0.f ? l3 : 0.2f * l3;
    return make_float4(__expf(l0), __expf(l1), __expf(l2), __expf(l3));
}

__device__ __forceinline__ float gelu_f(float v) {
    float u = 0.7978845608028654f * (v + 0.044715f * v * v * v);
    u = fminf(fmaxf(u, -15.f), 15.f);
    float t = __expf(2.f * u);
    return 0.5f * v * (1.f + (t - 1.f) / (t + 1.f));
}

// ------------------------------------------------------------------
// Stage 1: bin edges by dst/64. Each record carries {packed word, edge
// id} so alpha can be produced from the CSR side (alpha_edge deleted).
__global__ __launch_bounds__(256) void bin_edges(
    const int* __restrict__ src, const int* __restrict__ dst,
    const int* __restrict__ et,
    int* __restrict__ bincnt, int2* __restrict__ binwords,
    int E_, int nbins) {
    __shared__ int hist[NBMAX];
    __shared__ int base[NBMAX];
    int e0 = blockIdx.x * TILE;
    for (int i = threadIdx.x; i < nbins; i += 256) hist[i] = 0;
    __syncthreads();
    int mybin[8], myrank[8], myword[8];
#pragma unroll
    for (int u = 0; u < 8; ++u) {
        int e = e0 + u * 256 + threadIdx.x;
        mybin[u] = -1;
        if (e < E_) {
            int d = dst[e];
            int b = d >> BINB;
            myword[u] = src[e] | (et[e] << SRCB) | ((d & (BINSZ - 1)) << (SRCB + ETB));
            mybin[u] = b;
            myrank[u] = atomicAdd(&hist[b], 1);
        }
    }
    __syncthreads();
    for (int i = threadIdx.x; i < nbins; i += 256)
        base[i] = hist[i] > 0 ? atomicAdd(&bincnt[i], hist[i]) : 0;
    __syncthreads();
#pragma unroll
    for (int u = 0; u < 8; ++u) {
        if (mybin[u] >= 0) {
            int pos = base[mybin[u]] + myrank[u];
            if (pos < BINCAP)
                binwords[(size_t)mybin[u] * BINCAP + pos] =
                    make_int2(myword[u], e0 + u * 256 + threadIdx.x);
        }
    }
}

// ------------------------------------------------------------------
// Stage 2: one block per bin. Counting-sort by dlocal, compute ev, emit
// 16B CSR payload. ps[src] gathers are ISSUED in pass 1 (6 independent
// 16B gathers in flight, latency hidden under the rank-atomics + scan
// barriers) and consumed in pass 2. Edge id (20b) packed in spare bits:
//   pk.x = src_byteoff(24b) | e[7:0]<<24
//   pk.y = et_byteoff(13b)  | e[19:8]<<13
__global__ __launch_bounds__(256) void bin_sort(
    const int* __restrict__ bincnt, const int2* __restrict__ binwords,
    const float4* __restrict__ ps, const float* __restrict__ pdi,
    const float4* __restrict__ prg,
    int4* __restrict__ csr, int* __restrict__ noff, int* __restrict__ ncnt,
    int n, int R_) {
    __shared__ int cnts[BINSZ];
    __shared__ int scanb[BINSZ];
    __shared__ int nbase[BINSZ];
    __shared__ float4 pdl[BINSZ];
    __shared__ float4 prl[RMAX];
    int bin = blockIdx.x;
    int node0 = bin * BINSZ;
    int total = min(bincnt[bin], BINCAP);

    for (int i = threadIdx.x; i < BINSZ; i += 256) {
        cnts[i] = 0;
        int nd = node0 + i;
        pdl[i] = (nd < n) ? *reinterpret_cast<const float4*>(pdi + (size_t)nd * 8)
                          : make_float4(0.f, 0.f, 0.f, 0.f);
    }
    for (int i = threadIdx.x; i < R_; i += 256) prl[i] = prg[i];
    __syncthreads();

    // pass 1: load records, ISSUE ps gathers, per-node rank via LDS atomic
    int2 w[6];
    int rk[6];
    float4 psv[6];
#pragma unroll
    for (int u = 0; u < 6; ++u) {
        int k = u * 256 + threadIdx.x;
        rk[u] = -1;
        if (k < total) {
            w[u] = binwords[(size_t)bin * BINCAP + k];
            psv[u] = ps[w[u].x & SRCM];
            int dl = (w[u].x >> (SRCB + ETB)) & (BINSZ - 1);
            rk[u] = atomicAdd(&cnts[dl], 1);
        }
    }
    __syncthreads();

    // exclusive prefix over PADDED counts (round up to 4) -> nbase
    if (threadIdx.x < BINSZ) scanb[threadIdx.x] = (cnts[threadIdx.x] + 3) & ~3;
    __syncthreads();
    for (int s = 1; s < BINSZ; s <<= 1) {
        int v = 0;
        if (threadIdx.x < BINSZ && threadIdx.x >= s) v = scanb[threadIdx.x - s];
        __syncthreads();
        if (threadIdx.x < BINSZ) scanb[threadIdx.x] += v;
        __syncthreads();
    }
    if (threadIdx.x < BINSZ) {
        int cnt = cnts[threadIdx.x];
        int cntP = (cnt + 3) & ~3;
        int nb = scanb[threadIdx.x] - cntP;
        nbase[threadIdx.x] = nb;
        int nd = node0 + threadIdx.x;
        if (nd < n) {
            noff[nd] = bin * BINCAP + nb;
            ncnt[nd] = cnt;
        }
        // zero-fill pad entries (<=3 per node)
        int4 z = make_int4(0, 0, 0, 0);
        for (int i = cnt; i < cntP; ++i)
            csr[(size_t)bin * BINCAP + nb + i] = z;
    }
    // zero 12 entries past the bin's padded grand total (over-read window)
    {
        int gt = scanb[BINSZ - 1];
        if (threadIdx.x < 12) {
            int p = gt + threadIdx.x;
            if (p < BINCAP)
                csr[(size_t)bin * BINCAP + p] = make_int4(0, 0, 0, 0);
        }
    }
    __syncthreads();

    // pass 2: compute ev, write CSR payload sequentially per node
#pragma unroll
    for (int u = 0; u < 6; ++u) {
        if (rk[u] >= 0) {
            int s = w[u].x & SRCM;
            int t = (w[u].x >> SRCB) & ((1 << ETB) - 1);
            int dl = (w[u].x >> (SRCB + ETB)) & (BINSZ - 1);
            unsigned e = (unsigned)w[u].y;   // < 2^20
            float4 v = ev4(psv[u], pdl[dl], prl[t]);
            int4 pk;
            pk.x = (int)((unsigned)(s * (HIDC * 2)) | ((e & 0xFFu) << 24));
            pk.y = (int)((unsigned)(t * (HIDC * 2)) | ((e >> 8) << 13));
            pk.z = (int)h22u(__floats2half2_rn(v.x, v.y));
            pk.w = (int)h22u(__floats2half2_rn(v.z, v.w));
            csr[(size_t)bin * BINCAP + nbase[dl] + rk[u]] = pk;
        }
    }
}

// ------------------------------------------------------------------
// node_agg + fused alpha: R3-form main loop (best of seven variants),
// then a second pass over the node's CSR segment writes
// alpha[e] = ev * inv using the packed edge id.
__global__ __launch_bounds__(256) void node_agg(
    const __half* __restrict__ h16, const float* __restrict__ rel,
    const int4* __restrict__ csr, const int* __restrict__ noff,
    const int* __restrict__ ncnt,
    const float* __restrict__ bias,
    float* __restrict__ out, float4* __restrict__ alpha, int n, int R_) {
    __shared__ uint2 relh[RMAX * HIDC / 4];   // rel as fp16, 7.7 KB
    for (int i = threadIdx.x; i < R_ * 24; i += 256) {
        float4 v = reinterpret_cast<const float4*>(rel)[i];
        uint2 pk;
        pk.x = h22u(__floats2half2_rn(v.x, v.y));
        pk.y = h22u(__floats2half2_rn(v.z, v.w));
        relh[i] = pk;
    }
    __syncthreads();

    int lane = threadIdx.x & 31;
    if (lane >= 24) return;
    const int j = lane;
    const int j4 = 4 * j;
    const int hh = j / 6;
    const unsigned joff = (unsigned)(j << 3);   // byte offset within a 192 B row
    const float4 bv = *reinterpret_cast<const float4*>(bias + j4);
    const char* h16c = reinterpret_cast<const char*>(h16);
    const char* relc = reinterpret_cast<const char*>(relh);
    const unsigned esel = (unsigned)(2 * hh) | ((unsigned)(2 * hh + 1) << 8);

    int hw0 = (blockIdx.x * blockDim.x + threadIdx.x) >> 5;
    int nHW = (gridDim.x * blockDim.x) >> 5;

    for (int hw = hw0; hw < n; hw += nHW) {
        int cnt = ncnt[hw];
        const int4* sp0 = csr + noff[hw];
        const int4* sp = sp0;
        float a0 = 0.f, a1 = 0.f, a2 = 0.f, a3 = 0.f;
        float dsum = 0.f;

        if (cnt > 0) {
            int cntP = (cnt + 3) & ~3;   // segment is zero-padded to this
            int4 pc[4];
#pragma unroll
            for (int u = 0; u < 4; ++u) pc[u] = sp[u];
            sp += 4;

            for (int k = 0; k < cntP; k += 4, sp += 4) {
                uint2 hv[4], rv[4];
#pragma unroll
                for (int u = 0; u < 4; ++u)
                    hv[u] = *reinterpret_cast<const uint2*>(
                        h16c + ((unsigned)pc[u].x & 0x00FFFFFFu) + joff);
#pragma unroll
                for (int u = 0; u < 4; ++u)
                    rv[u] = *reinterpret_cast<const uint2*>(
                        relc + ((unsigned)pc[u].y & 0x1FFFu) + joff);
                int4 pn[4];
#pragma unroll
                for (int u = 0; u < 4; ++u) pn[u] = sp[u];
#pragma unroll
                for (int u = 0; u < 4; ++u) {
                    unsigned e32 = __builtin_amdgcn_perm(
                        (unsigned)pc[u].w, (unsigned)pc[u].z, esel);
                    dsum += __half2float(__low2half(u2h2(e32)));
                    unsigned s01 = h22u(__hadd2(u2h2(hv[u].x), u2h2(rv[u].x)));
                    unsigned s23 = h22u(__hadd2(u2h2(hv[u].y), u2h2(rv[u].y)));
                    asm("v_fma_mix_f32 %0, %1, %2, %0 op_sel:[0,0,0] op_sel_hi:[1,1,0]"
                        : "+v"(a0) : "v"(s01), "v"(e32));
                    asm("v_fma_mix_f32 %0, %1, %2, %0 op_sel:[1,0,0] op_sel_hi:[1,1,0]"
                        : "+v"(a1) : "v"(s01), "v"(e32));
                    asm("v_fma_mix_f32 %0, %1, %2, %0 op_sel:[0,0,0] op_sel_hi:[1,1,0]"
                        : "+v"(a2) : "v"(s23), "v"(e32));
                    asm("v_fma_mix_f32 %0, %1, %2, %0 op_sel:[1,0,0] op_sel_hi:[1,1,0]"
                        : "+v"(a3) : "v"(s23), "v"(e32));
                }
#pragma unroll
                for (int u = 0; u < 4; ++u) pc[u] = pn[u];
            }
        }
        float inv = dsum > 0.f ? 1.f / dsum : 0.f;
        float4 o;
        o.x = gelu_f(a0 * inv + bv.x);
        o.y = gelu_f(a1 * inv + bv.y);
        o.z = gelu_f(a2 * inv + bv.z);
        o.w = gelu_f(a3 * inv + bv.w);
        *reinterpret_cast<float4*>(out + (size_t)hw * HIDC + j4) = o;

        // fused alpha: inv for all 4 heads via intra-half shuffles, then
        // each lane handles edges j, j+24, ... (exact cnt bound: pads and
        // over-read window never produce writes).
        if (cnt > 0) {
            float iv0 = __shfl(inv, 0, 32);
            float iv1 = __shfl(inv, 6, 32);
            float iv2 = __shfl(inv, 12, 32);
            float iv3 = __shfl(inv, 18, 32);
            for (int k = j; k < cnt; k += 24) {
                int4 pk = sp0[k];
                unsigned e_id = ((unsigned)pk.x >> 24) | (((unsigned)pk.y >> 13) << 8);
                float2 f01 = __half22float2(u2h2((unsigned)pk.z));
                float2 f23 = __half22float2(u2h2((unsigned)pk.w));
                alpha[e_id] = make_float4(f01.x * iv0, f01.y * iv1,
                                          f23.x * iv2, f23.y * iv3);
            }
        }
    }
}

// ------------------------------------------------------------------
extern "C" void kernel_launch(void* const* d_in, const int* in_sizes, int n_in,
                              void* d_out, int out_size, void* d_ws, size_t ws_size,
                              hipStream_t stream) {
    const float* x       = (const float*)d_in[0];
    const int*   eidx    = (const int*)d_in[1];
    const int*   etype   = (const int*)d_in[2];
    const float* W       = (const float*)d_in[3];
    const float* rel     = (const float*)d_in[4];
    const float* att_src = (const float*)d_in[5];
    const float* att_dst = (const float*)d_in[6];
    const float* att_rel = (const float*)d_in[7];
    const float* bias    = (const float*)d_in[8];

    int N_ = in_sizes[0] / HIDC;
    int E_ = in_sizes[1] / 2;
    int R_ = in_sizes[4] / HIDC;
    const int* src  = eidx;
    const int* dstp = eidx + E_;
    int nbins = (N_ + BINSZ - 1) / BINSZ;

    // workspace layout (16B-aligned chunks), ~38 MB total
    char* ws = (char*)d_ws;
    __half* h16      = (__half*)ws; ws += (size_t)N_ * HIDC * 2;        // 9.6 MB
    float4* ps       = (float4*)ws; ws += (size_t)N_ * 16;              // 0.8 MB
    float*  pdi      = (float*)ws;  ws += (size_t)N_ * 32;              // 1.6 MB (pd | spare)
    float4* pr       = (float4*)ws; ws += 1024;
    int*    bincnt   = (int*)ws;    ws += (size_t)((nbins + 3) & ~3) * 4;
    int*    noff     = (int*)ws;    ws += (size_t)((N_ + 3) & ~3) * 4;  // 0.2 MB
    int*    ncnt     = (int*)ws;    ws += (size_t)((N_ + 3) & ~3) * 4;  // 0.2 MB
    int2*   binwords = (int2*)ws;   ws += (size_t)nbins * BINCAP * 8;   // 8.4 MB
    int4*   csr      = (int4*)ws;   ws += (size_t)nbins * BINCAP * 16 + 256; // 16.8 MB (+slack)

    float*  outv  = (float*)d_out;                       // N*96
    float4* alpha = (float4*)(outv + (size_t)N_ * HIDC); // E*4

    gemm96<<<(N_ + 63) / 64, 256, 0, stream>>>(
        x, W, h16, bincnt, csr + (size_t)nbins * BINCAP, N_, nbins);

    node_dots<<<(N_ + 255) / 256 + 1, 256, 0, stream>>>(
        h16, att_src, att_dst, rel, att_rel, ps, pdi, pr, N_, R_);

    bin_edges<<<(E_ + TILE - 1) / TILE, 256, 0, stream>>>(
        src, dstp, etype, bincnt, binwords, E_, nbins);

    bin_sort<<<nbins, 256, 0, stream>>>(
        bincnt, binwords, ps, pdi, pr, csr, noff, ncnt, N_, R_);

    node_agg<<<(N_ + 15) / 16, 256, 0, stream>>>(
        h16, rel, csr, noff, ncnt, bias, outv, alpha, N_, R_);
}

// Round 15
// 172.798 us; speedup vs baseline: 1.1783x; 1.0264x over previous
//
#include <hip/hip_runtime.h>
#include <hip/hip_fp16.h>
#include <math.h>

#define HIDC 96
#define HEADS 4
#define RMAX 40    // max relations staged in LDS (bench: R=38)
#define BINSZ 64   // dst nodes per bin (dlocal fits 6 bits)
#define BINB 6
#define BINCAP 1344 // words per bin region (Poisson 1024 + pad ~96: +6.8 sigma)
#define TILE 2048  // edges per bin_edges tile
#define SRCB 18    // src bits (N < 262144)
#define SRCM ((1 << SRCB) - 1)
#define ETB 6      // et bits (R < 64)
#define NBMAX 1024 // LDS histogram capacity (nbins = 782 at N=50K)

typedef unsigned u32x2 __attribute__((ext_vector_type(2)));
typedef _Float16 f16x4 __attribute__((ext_vector_type(4)));
typedef float f32x4 __attribute__((ext_vector_type(4)));

__device__ __forceinline__ __half2 u2h2(unsigned u) {
    return *reinterpret_cast<__half2*>(&u);
}
__device__ __forceinline__ unsigned h22u(__half2 h) {
    return *reinterpret_cast<unsigned*>(&h);
}

// ------------------------------------------------------------------
// h16 = half(x @ W) via MFMA f16, with node_dots FUSED into the
// register epilogue: the accumulator tile c[nt][i] holds the projected
// features, so ps/pd dot-products are computed with per-lane partial
// sums + 16-lane shfl_xor butterflies instead of re-reading 9.6 MB of
// h16 in a separate kernel. pr (per-relation dots) rides on block 0.
// Also zeroes bin counters + csr global tail.
__global__ __launch_bounds__(256) void gemm96(
    const float* __restrict__ x, const float* __restrict__ W,
    const float* __restrict__ att_src, const float* __restrict__ att_dst,
    const float* __restrict__ rel, const float* __restrict__ att_rel,
    __half* __restrict__ h16, float4* __restrict__ ps,
    float* __restrict__ pdi, float4* __restrict__ pr,
    int* __restrict__ bincnt, int4* __restrict__ csrtail,
    int n, int nbins, int R_) {
    for (int i = blockIdx.x * 256 + threadIdx.x; i < nbins; i += gridDim.x * 256)
        bincnt[i] = 0;
    if (blockIdx.x == 0 && threadIdx.x < 16)
        csrtail[threadIdx.x] = make_int4(0, 0, 0, 0);   // slack past last bin
    if (blockIdx.x == 0 && threadIdx.x < R_) {
        int t = threadIdx.x;
        const float4* rp = reinterpret_cast<const float4*>(rel + (size_t)t * HIDC);
        const float4* ar = reinterpret_cast<const float4*>(att_rel);
        float acc[HEADS] = {0, 0, 0, 0};
#pragma unroll
        for (int c = 0; c < 24; ++c) {
            float4 v = rp[c], a = ar[c];
            acc[c / 6] += v.x * a.x + v.y * a.y + v.z * a.z + v.w * a.w;
        }
        pr[t] = make_float4(acc[0], acc[1], acc[2], acc[3]);
    }

    const int lane = threadIdx.x & 63;
    const int wave = threadIdx.x >> 6;
    const int lo16 = lane & 15;
    const int grp = lane >> 4;          // 0..3

    // B fragments: bf[kf][nt], lane holds W[kf*16+4*grp+j][nt*16+lo16]
    f16x4 bf[6][6];
#pragma unroll
    for (int kf = 0; kf < 6; ++kf)
#pragma unroll
        for (int nt = 0; nt < 6; ++nt) {
            f16x4 b;
#pragma unroll
            for (int j = 0; j < 4; ++j)
                b[j] = (_Float16)W[(kf * 16 + grp * 4 + j) * HIDC + nt * 16 + lo16];
            bf[kf][nt] = b;
        }

    int row0 = blockIdx.x * 64 + wave * 16;
    if (row0 >= n) return;
    int r = row0 + lo16;
    const float4* xr = reinterpret_cast<const float4*>(
        x + (size_t)min(r, n - 1) * HIDC);

    f32x4 c[6];
#pragma unroll
    for (int nt = 0; nt < 6; ++nt) c[nt] = (f32x4){0.f, 0.f, 0.f, 0.f};

#pragma unroll
    for (int kf = 0; kf < 6; ++kf) {
        float4 av = xr[kf * 4 + grp];   // cols 16*kf + 4*grp .. +3
        f16x4 af;
        af[0] = (_Float16)av.x; af[1] = (_Float16)av.y;
        af[2] = (_Float16)av.z; af[3] = (_Float16)av.w;
#pragma unroll
        for (int nt = 0; nt < 6; ++nt)
            c[nt] = __builtin_amdgcn_mfma_f32_16x16x16f16(af, bf[kf][nt], c[nt], 0, 0, 0);
    }

#pragma unroll
    for (int nt = 0; nt < 6; ++nt)
#pragma unroll
        for (int i = 0; i < 4; ++i) {
            int rr = row0 + grp * 4 + i;
            if (rr < n)
                h16[(size_t)rr * HIDC + nt * 16 + lo16] = (__half)c[nt][i];
        }

    // ---- fused node_dots ----
    // lane's col for fragment nt is nt*16+lo16; att_* are flat 96 floats.
    // Head boundaries (24/48/72) split only nt=1 and nt=4 at lo16==8.
    float as_[6], ad_[6];
#pragma unroll
    for (int nt = 0; nt < 6; ++nt) {
        as_[nt] = att_src[nt * 16 + lo16];
        ad_[nt] = att_dst[nt * 16 + lo16];
    }
    bool lo8 = lo16 < 8;
    float a1lo = lo8 ? as_[1] : 0.f, a1hi = lo8 ? 0.f : as_[1];
    float d1lo = lo8 ? ad_[1] : 0.f, d1hi = lo8 ? 0.f : ad_[1];
    float a4lo = lo8 ? as_[4] : 0.f, a4hi = lo8 ? 0.f : as_[4];
    float d4lo = lo8 ? ad_[4] : 0.f, d4hi = lo8 ? 0.f : ad_[4];

    float sA[4][4], sD[4][4];
#pragma unroll
    for (int i = 0; i < 4; ++i) {
        float v0 = c[0][i], v1 = c[1][i], v2 = c[2][i];
        float v3 = c[3][i], v4 = c[4][i], v5 = c[5][i];
        sA[i][0] = v0 * as_[0] + v1 * a1lo;
        sA[i][1] = v1 * a1hi + v2 * as_[2];
        sA[i][2] = v3 * as_[3] + v4 * a4lo;
        sA[i][3] = v4 * a4hi + v5 * as_[5];
        sD[i][0] = v0 * ad_[0] + v1 * d1lo;
        sD[i][1] = v1 * d1hi + v2 * ad_[2];
        sD[i][2] = v3 * ad_[3] + v4 * d4lo;
        sD[i][3] = v4 * d4hi + v5 * ad_[5];
    }
    // butterfly over the 16-lane group (masks 1,2,4,8 stay in-group)
#pragma unroll
    for (int i = 0; i < 4; ++i)
#pragma unroll
        for (int h = 0; h < 4; ++h) {
#pragma unroll
            for (int m = 1; m < 16; m <<= 1) {
                sA[i][h] += __shfl_xor(sA[i][h], m);
                sD[i][h] += __shfl_xor(sD[i][h], m);
            }
        }
    // lanes lo16==0..3 of each grp write that grp's 4 rows
    {
        int rr = row0 + grp * 4 + lo16;
        if (lo16 < 4 && rr < n) {
            float4 pv, dv;
            if (lo16 == 0) {
                pv = make_float4(sA[0][0], sA[0][1], sA[0][2], sA[0][3]);
                dv = make_float4(sD[0][0], sD[0][1], sD[0][2], sD[0][3]);
            } else if (lo16 == 1) {
                pv = make_float4(sA[1][0], sA[1][1], sA[1][2], sA[1][3]);
                dv = make_float4(sD[1][0], sD[1][1], sD[1][2], sD[1][3]);
            } else if (lo16 == 2) {
                pv = make_float4(sA[2][0], sA[2][1], sA[2][2], sA[2][3]);
                dv = make_float4(sD[2][0], sD[2][1], sD[2][2], sD[2][3]);
            } else {
                pv = make_float4(sA[3][0], sA[3][1], sA[3][2], sA[3][3]);
                dv = make_float4(sD[3][0], sD[3][1], sD[3][2], sD[3][3]);
            }
            ps[rr] = pv;
            *reinterpret_cast<float4*>(pdi + (size_t)rr * 8) = dv;
        }
    }
}

// ------------------------------------------------------------------
__device__ __forceinline__ float4 ev4(float4 a, float4 b, float4 c) {
    float l0 = a.x + b.x + c.x, l1 = a.y + b.y + c.y;
    float l2 = a.z + b.z + c.z, l3 = a.w + b.w + c.w;
    l0 = l0 >= 0.f ? l0 : 0.2f * l0;
    l1 = l1 >= 0.f ? l1 : 0.2f * l1;
    l2 = l2 >= 0.f ? l2 : 0.2f * l2;
    l3 = l3 >= 0.f ? l3 : 0.2f * l3;
    return make_float4(__expf(l0), __expf(l1), __expf(l2), __expf(l3));
}

__device__ __forceinline__ float gelu_f(float v) {
    float u = 0.7978845608028654f * (v + 0.044715f * v * v * v);
    u = fminf(fmaxf(u, -15.f), 15.f);
    float t = __expf(2.f * u);
    return 0.5f * v * (1.f + (t - 1.f) / (t + 1.f));
}

// ------------------------------------------------------------------
// Stage 1: bin edges by dst/64. Each record carries {packed word, edge
// id} so alpha can be produced from the CSR side (alpha_edge deleted).
__global__ __launch_bounds__(256) void bin_edges(
    const int* __restrict__ src, const int* __restrict__ dst,
    const int* __restrict__ et,
    int* __restrict__ bincnt, int2* __restrict__ binwords,
    int E_, int nbins) {
    __shared__ int hist[NBMAX];
    __shared__ int base[NBMAX];
    int e0 = blockIdx.x * TILE;
    for (int i = threadIdx.x; i < nbins; i += 256) hist[i] = 0;
    __syncthreads();
    int mybin[8], myrank[8], myword[8];
#pragma unroll
    for (int u = 0; u < 8; ++u) {
        int e = e0 + u * 256 + threadIdx.x;
        mybin[u] = -1;
        if (e < E_) {
            int d = dst[e];
            int b = d >> BINB;
            myword[u] = src[e] | (et[e] << SRCB) | ((d & (BINSZ - 1)) << (SRCB + ETB));
            mybin[u] = b;
            myrank[u] = atomicAdd(&hist[b], 1);
        }
    }
    __syncthreads();
    for (int i = threadIdx.x; i < nbins; i += 256)
        base[i] = hist[i] > 0 ? atomicAdd(&bincnt[i], hist[i]) : 0;
    __syncthreads();
#pragma unroll
    for (int u = 0; u < 8; ++u) {
        if (mybin[u] >= 0) {
            int pos = base[mybin[u]] + myrank[u];
            if (pos < BINCAP)
                binwords[(size_t)mybin[u] * BINCAP + pos] =
                    make_int2(myword[u], e0 + u * 256 + threadIdx.x);
        }
    }
}

// ------------------------------------------------------------------
// Stage 2: one block per bin. Counting-sort by dlocal, compute ev, emit
// 16B CSR payload. ps gathers issued in pass 1 (latency hidden under
// rank atomics + scan). Scan is a single-wave shfl_up butterfly (BINSZ
// = 64 = 1 wave) — the 12-barrier Hillis-Steele is gone. Edge id (20b)
// packed: pk.x = src_byteoff(24b)|e[7:0]<<24; pk.y = et_off(13b)|e[19:8]<<13.
__global__ __launch_bounds__(256) void bin_sort(
    const int* __restrict__ bincnt, const int2* __restrict__ binwords,
    const float4* __restrict__ ps, const float* __restrict__ pdi,
    const float4* __restrict__ prg,
    int4* __restrict__ csr, int* __restrict__ noff, int* __restrict__ ncnt,
    int n, int R_) {
    __shared__ int cnts[BINSZ];
    __shared__ int scanb[BINSZ];
    __shared__ int nbase[BINSZ];
    __shared__ float4 pdl[BINSZ];
    __shared__ float4 prl[RMAX];
    int bin = blockIdx.x;
    int node0 = bin * BINSZ;
    int total = min(bincnt[bin], BINCAP);

    for (int i = threadIdx.x; i < BINSZ; i += 256) {
        cnts[i] = 0;
        int nd = node0 + i;
        pdl[i] = (nd < n) ? *reinterpret_cast<const float4*>(pdi + (size_t)nd * 8)
                          : make_float4(0.f, 0.f, 0.f, 0.f);
    }
    for (int i = threadIdx.x; i < R_; i += 256) prl[i] = prg[i];
    __syncthreads();

    // pass 1: load records, ISSUE ps gathers, per-node rank via LDS atomic
    int2 w[6];
    int rk[6];
    float4 psv[6];
#pragma unroll
    for (int u = 0; u < 6; ++u) {
        int k = u * 256 + threadIdx.x;
        rk[u] = -1;
        if (k < total) {
            w[u] = binwords[(size_t)bin * BINCAP + k];
            psv[u] = ps[w[u].x & SRCM];
            int dl = (w[u].x >> (SRCB + ETB)) & (BINSZ - 1);
            rk[u] = atomicAdd(&cnts[dl], 1);
        }
    }
    __syncthreads();

    // single-wave inclusive scan of PADDED counts -> scanb
    if (threadIdx.x < 64) {
        int v = (cnts[threadIdx.x] + 3) & ~3;
#pragma unroll
        for (int s = 1; s < 64; s <<= 1) {
            int t = __shfl_up(v, s, 64);
            if ((int)threadIdx.x >= s) v += t;
        }
        scanb[threadIdx.x] = v;
    }
    __syncthreads();
    if (threadIdx.x < BINSZ) {
        int cnt = cnts[threadIdx.x];
        int cntP = (cnt + 3) & ~3;
        int nb = scanb[threadIdx.x] - cntP;
        nbase[threadIdx.x] = nb;
        int nd = node0 + threadIdx.x;
        if (nd < n) {
            noff[nd] = bin * BINCAP + nb;
            ncnt[nd] = cnt;
        }
        // zero-fill pad entries (<=3 per node)
        int4 z = make_int4(0, 0, 0, 0);
        for (int i = cnt; i < cntP; ++i)
            csr[(size_t)bin * BINCAP + nb + i] = z;
    }
    // zero 12 entries past the bin's padded grand total (over-read window)
    {
        int gt = scanb[BINSZ - 1];
        if (threadIdx.x < 12) {
            int p = gt + threadIdx.x;
            if (p < BINCAP)
                csr[(size_t)bin * BINCAP + p] = make_int4(0, 0, 0, 0);
        }
    }
    __syncthreads();

    // pass 2: compute ev, write CSR payload sequentially per node
#pragma unroll
    for (int u = 0; u < 6; ++u) {
        if (rk[u] >= 0) {
            int s = w[u].x & SRCM;
            int t = (w[u].x >> SRCB) & ((1 << ETB) - 1);
            int dl = (w[u].x >> (SRCB + ETB)) & (BINSZ - 1);
            unsigned e = (unsigned)w[u].y;   // < 2^20
            float4 v = ev4(psv[u], pdl[dl], prl[t]);
            int4 pk;
            pk.x = (int)((unsigned)(s * (HIDC * 2)) | ((e & 0xFFu) << 24));
            pk.y = (int)((unsigned)(t * (HIDC * 2)) | ((e >> 8) << 13));
            pk.z = (int)h22u(__floats2half2_rn(v.x, v.y));
            pk.w = (int)h22u(__floats2half2_rn(v.z, v.w));
            csr[(size_t)bin * BINCAP + nbase[dl] + rk[u]] = pk;
        }
    }
}

// ------------------------------------------------------------------
// node_agg + fused alpha: R3-form main loop (best of seven variants),
// then a second pass over the node's CSR segment writes
// alpha[e] = ev * inv using the packed edge id.
__global__ __launch_bounds__(256) void node_agg(
    const __half* __restrict__ h16, const float* __restrict__ rel,
    const int4* __restrict__ csr, const int* __restrict__ noff,
    const int* __restrict__ ncnt,
    const float* __restrict__ bias,
    float* __restrict__ out, float4* __restrict__ alpha, int n, int R_) {
    __shared__ uint2 relh[RMAX * HIDC / 4];   // rel as fp16, 7.7 KB
    for (int i = threadIdx.x; i < R_ * 24; i += 256) {
        float4 v = reinterpret_cast<const float4*>(rel)[i];
        uint2 pk;
        pk.x = h22u(__floats2half2_rn(v.x, v.y));
        pk.y = h22u(__floats2half2_rn(v.z, v.w));
        relh[i] = pk;
    }
    __syncthreads();

    int lane = threadIdx.x & 31;
    if (lane >= 24) return;
    const int j = lane;
    const int j4 = 4 * j;
    const int hh = j / 6;
    const unsigned joff = (unsigned)(j << 3);   // byte offset within a 192 B row
    const float4 bv = *reinterpret_cast<const float4*>(bias + j4);
    const char* h16c = reinterpret_cast<const char*>(h16);
    const char* relc = reinterpret_cast<const char*>(relh);
    const unsigned esel = (unsigned)(2 * hh) | ((unsigned)(2 * hh + 1) << 8);

    int hw0 = (blockIdx.x * blockDim.x + threadIdx.x) >> 5;
    int nHW = (gridDim.x * blockDim.x) >> 5;

    for (int hw = hw0; hw < n; hw += nHW) {
        int cnt = ncnt[hw];
        const int4* sp0 = csr + noff[hw];
        const int4* sp = sp0;
        float a0 = 0.f, a1 = 0.f, a2 = 0.f, a3 = 0.f;
        float dsum = 0.f;

        if (cnt > 0) {
            int cntP = (cnt + 3) & ~3;   // segment is zero-padded to this
            int4 pc[4];
#pragma unroll
            for (int u = 0; u < 4; ++u) pc[u] = sp[u];
            sp += 4;

            for (int k = 0; k < cntP; k += 4, sp += 4) {
                uint2 hv[4], rv[4];
#pragma unroll
                for (int u = 0; u < 4; ++u)
                    hv[u] = *reinterpret_cast<const uint2*>(
                        h16c + ((unsigned)pc[u].x & 0x00FFFFFFu) + joff);
#pragma unroll
                for (int u = 0; u < 4; ++u)
                    rv[u] = *reinterpret_cast<const uint2*>(
                        relc + ((unsigned)pc[u].y & 0x1FFFu) + joff);
                int4 pn[4];
#pragma unroll
                for (int u = 0; u < 4; ++u) pn[u] = sp[u];
#pragma unroll
                for (int u = 0; u < 4; ++u) {
                    unsigned e32 = __builtin_amdgcn_perm(
                        (unsigned)pc[u].w, (unsigned)pc[u].z, esel);
                    dsum += __half2float(__low2half(u2h2(e32)));
                    unsigned s01 = h22u(__hadd2(u2h2(hv[u].x), u2h2(rv[u].x)));
                    unsigned s23 = h22u(__hadd2(u2h2(hv[u].y), u2h2(rv[u].y)));
                    asm("v_fma_mix_f32 %0, %1, %2, %0 op_sel:[0,0,0] op_sel_hi:[1,1,0]"
                        : "+v"(a0) : "v"(s01), "v"(e32));
                    asm("v_fma_mix_f32 %0, %1, %2, %0 op_sel:[1,0,0] op_sel_hi:[1,1,0]"
                        : "+v"(a1) : "v"(s01), "v"(e32));
                    asm("v_fma_mix_f32 %0, %1, %2, %0 op_sel:[0,0,0] op_sel_hi:[1,1,0]"
                        : "+v"(a2) : "v"(s23), "v"(e32));
                    asm("v_fma_mix_f32 %0, %1, %2, %0 op_sel:[1,0,0] op_sel_hi:[1,1,0]"
                        : "+v"(a3) : "v"(s23), "v"(e32));
                }
#pragma unroll
                for (int u = 0; u < 4; ++u) pc[u] = pn[u];
            }
        }
        float inv = dsum > 0.f ? 1.f / dsum : 0.f;
        float4 o;
        o.x = gelu_f(a0 * inv + bv.x);
        o.y = gelu_f(a1 * inv + bv.y);
        o.z = gelu_f(a2 * inv + bv.z);
        o.w = gelu_f(a3 * inv + bv.w);
        *reinterpret_cast<float4*>(out + (size_t)hw * HIDC + j4) = o;

        // fused alpha: inv for all 4 heads via intra-half shuffles, then
        // each lane handles edges j, j+24, ... (exact cnt bound: pads and
        // over-read window never produce writes).
        if (cnt > 0) {
            float iv0 = __shfl(inv, 0, 32);
            float iv1 = __shfl(inv, 6, 32);
            float iv2 = __shfl(inv, 12, 32);
            float iv3 = __shfl(inv, 18, 32);
            for (int k = j; k < cnt; k += 24) {
                int4 pk = sp0[k];
                unsigned e_id = ((unsigned)pk.x >> 24) | (((unsigned)pk.y >> 13) << 8);
                float2 f01 = __half22float2(u2h2((unsigned)pk.z));
                float2 f23 = __half22float2(u2h2((unsigned)pk.w));
                alpha[e_id] = make_float4(f01.x * iv0, f01.y * iv1,
                                          f23.x * iv2, f23.y * iv3);
            }
        }
    }
}

// ------------------------------------------------------------------
extern "C" void kernel_launch(void* const* d_in, const int* in_sizes, int n_in,
                              void* d_out, int out_size, void* d_ws, size_t ws_size,
                              hipStream_t stream) {
    const float* x       = (const float*)d_in[0];
    const int*   eidx    = (const int*)d_in[1];
    const int*   etype   = (const int*)d_in[2];
    const float* W       = (const float*)d_in[3];
    const float* rel     = (const float*)d_in[4];
    const float* att_src = (const float*)d_in[5];
    const float* att_dst = (const float*)d_in[6];
    const float* att_rel = (const float*)d_in[7];
    const float* bias    = (const float*)d_in[8];

    int N_ = in_sizes[0] / HIDC;
    int E_ = in_sizes[1] / 2;
    int R_ = in_sizes[4] / HIDC;
    const int* src  = eidx;
    const int* dstp = eidx + E_;
    int nbins = (N_ + BINSZ - 1) / BINSZ;

    // workspace layout (16B-aligned chunks), ~38 MB total
    char* ws = (char*)d_ws;
    __half* h16      = (__half*)ws; ws += (size_t)N_ * HIDC * 2;        // 9.6 MB
    float4* ps       = (float4*)ws; ws += (size_t)N_ * 16;              // 0.8 MB
    float*  pdi      = (float*)ws;  ws += (size_t)N_ * 32;              // 1.6 MB (pd | spare)
    float4* pr       = (float4*)ws; ws += 1024;
    int*    bincnt   = (int*)ws;    ws += (size_t)((nbins + 3) & ~3) * 4;
    int*    noff     = (int*)ws;    ws += (size_t)((N_ + 3) & ~3) * 4;  // 0.2 MB
    int*    ncnt     = (int*)ws;    ws += (size_t)((N_ + 3) & ~3) * 4;  // 0.2 MB
    int2*   binwords = (int2*)ws;   ws += (size_t)nbins * BINCAP * 8;   // 8.4 MB
    int4*   csr      = (int4*)ws;   ws += (size_t)nbins * BINCAP * 16 + 256; // 16.8 MB (+slack)

    float*  outv  = (float*)d_out;                       // N*96
    float4* alpha = (float4*)(outv + (size_t)N_ * HIDC); // E*4

    gemm96<<<(N_ + 63) / 64, 256, 0, stream>>>(
        x, W, att_src, att_dst, rel, att_rel, h16, ps, pdi, pr,
        bincnt, csr + (size_t)nbins * BINCAP, N_, nbins, R_);

    bin_edges<<<(E_ + TILE - 1) / TILE, 256, 0, stream>>>(
        src, dstp, etype, bincnt, binwords, E_, nbins);

    bin_sort<<<nbins, 256, 0, stream>>>(
        bincnt, binwords, ps, pdi, pr, csr, noff, ncnt, N_, R_);

    node_agg<<<(N_ + 15) / 16, 256, 0, stream>>>(
        h16, rel, csr, noff, ncnt, bias, outv, alpha, N_, R_);
}

// Round 16
// 172.485 us; speedup vs baseline: 1.1804x; 1.0018x over previous
//
#include <hip/hip_runtime.h>
#include <hip/hip_fp16.h>
#include <math.h>

#define HIDC 96
#define HEADS 4
#define RMAX 40    // max relations staged in LDS (bench: R=38)
#define BINSZ 64   // dst nodes per bin (dlocal fits 6 bits)
#define BINB 6
#define BINCAP 1344 // words per bin region (Poisson 1024 + pad ~96: +6.8 sigma)
#define TILE 2048  // edges per bin_edges tile
#define SRCB 18    // src bits (N < 262144)
#define SRCM ((1 << SRCB) - 1)
#define ETB 6      // et bits (R < 64)
#define NBMAX 1024 // LDS histogram capacity (nbins = 782 at N=50K)

typedef unsigned u32x2 __attribute__((ext_vector_type(2)));
typedef _Float16 f16x4 __attribute__((ext_vector_type(4)));
typedef float f32x4 __attribute__((ext_vector_type(4)));

__device__ __forceinline__ __half2 u2h2(unsigned u) {
    return *reinterpret_cast<__half2*>(&u);
}
__device__ __forceinline__ unsigned h22u(__half2 h) {
    return *reinterpret_cast<unsigned*>(&h);
}

// ------------------------------------------------------------------
// FUSED kernel: blocks [0, gemmBlocks) run the MFMA GEMM + fused
// node_dots epilogue; blocks [gemmBlocks, +edgeBlocks) run bin_edges.
// The two are data-independent -> they overlap in hardware instead of
// serializing as two launches. bincnt/csrtail are pre-zeroed by
// hipMemsetAsync (graph-capture-safe), removing the ordering hazard.
__global__ __launch_bounds__(256) void gemm_bin(
    const float* __restrict__ x, const float* __restrict__ W,
    const float* __restrict__ att_src, const float* __restrict__ att_dst,
    const float* __restrict__ rel, const float* __restrict__ att_rel,
    __half* __restrict__ h16, float4* __restrict__ ps,
    float* __restrict__ pdi, float4* __restrict__ pr,
    const int* __restrict__ srcp, const int* __restrict__ dstp,
    const int* __restrict__ etp,
    int* __restrict__ bincnt, int2* __restrict__ binwords,
    int n, int nbins, int R_, int E_, int gemmBlocks) {

    if ((int)blockIdx.x >= gemmBlocks) {
        // ---------------- bin_edges path ----------------
        __shared__ int hist[NBMAX];
        __shared__ int base[NBMAX];
        int bid = blockIdx.x - gemmBlocks;
        int e0 = bid * TILE;
        for (int i = threadIdx.x; i < nbins; i += 256) hist[i] = 0;
        __syncthreads();
        int mybin[8], myrank[8], myword[8];
#pragma unroll
        for (int u = 0; u < 8; ++u) {
            int e = e0 + u * 256 + threadIdx.x;
            mybin[u] = -1;
            if (e < E_) {
                int d = dstp[e];
                int b = d >> BINB;
                myword[u] = srcp[e] | (etp[e] << SRCB) |
                            ((d & (BINSZ - 1)) << (SRCB + ETB));
                mybin[u] = b;
                myrank[u] = atomicAdd(&hist[b], 1);
            }
        }
        __syncthreads();
        for (int i = threadIdx.x; i < nbins; i += 256)
            base[i] = hist[i] > 0 ? atomicAdd(&bincnt[i], hist[i]) : 0;
        __syncthreads();
#pragma unroll
        for (int u = 0; u < 8; ++u) {
            if (mybin[u] >= 0) {
                int pos = base[mybin[u]] + myrank[u];
                if (pos < BINCAP)
                    binwords[(size_t)mybin[u] * BINCAP + pos] =
                        make_int2(myword[u], e0 + u * 256 + threadIdx.x);
            }
        }
        return;
    }

    // ---------------- GEMM + node_dots path ----------------
    if (blockIdx.x == 0 && threadIdx.x < R_) {
        int t = threadIdx.x;
        const float4* rp = reinterpret_cast<const float4*>(rel + (size_t)t * HIDC);
        const float4* ar = reinterpret_cast<const float4*>(att_rel);
        float acc[HEADS] = {0, 0, 0, 0};
#pragma unroll
        for (int c = 0; c < 24; ++c) {
            float4 v = rp[c], a = ar[c];
            acc[c / 6] += v.x * a.x + v.y * a.y + v.z * a.z + v.w * a.w;
        }
        pr[t] = make_float4(acc[0], acc[1], acc[2], acc[3]);
    }

    const int lane = threadIdx.x & 63;
    const int wave = threadIdx.x >> 6;
    const int lo16 = lane & 15;
    const int grp = lane >> 4;          // 0..3

    // B fragments: bf[kf][nt], lane holds W[kf*16+4*grp+j][nt*16+lo16]
    f16x4 bf[6][6];
#pragma unroll
    for (int kf = 0; kf < 6; ++kf)
#pragma unroll
        for (int nt = 0; nt < 6; ++nt) {
            f16x4 b;
#pragma unroll
            for (int j = 0; j < 4; ++j)
                b[j] = (_Float16)W[(kf * 16 + grp * 4 + j) * HIDC + nt * 16 + lo16];
            bf[kf][nt] = b;
        }

    int row0 = blockIdx.x * 64 + wave * 16;
    if (row0 >= n) return;
    int r = row0 + lo16;
    const float4* xr = reinterpret_cast<const float4*>(
        x + (size_t)min(r, n - 1) * HIDC);

    f32x4 c[6];
#pragma unroll
    for (int nt = 0; nt < 6; ++nt) c[nt] = (f32x4){0.f, 0.f, 0.f, 0.f};

#pragma unroll
    for (int kf = 0; kf < 6; ++kf) {
        float4 av = xr[kf * 4 + grp];   // cols 16*kf + 4*grp .. +3
        f16x4 af;
        af[0] = (_Float16)av.x; af[1] = (_Float16)av.y;
        af[2] = (_Float16)av.z; af[3] = (_Float16)av.w;
#pragma unroll
        for (int nt = 0; nt < 6; ++nt)
            c[nt] = __builtin_amdgcn_mfma_f32_16x16x16f16(af, bf[kf][nt], c[nt], 0, 0, 0);
    }

#pragma unroll
    for (int nt = 0; nt < 6; ++nt)
#pragma unroll
        for (int i = 0; i < 4; ++i) {
            int rr = row0 + grp * 4 + i;
            if (rr < n)
                h16[(size_t)rr * HIDC + nt * 16 + lo16] = (__half)c[nt][i];
        }

    // ---- fused node_dots ----
    float as_[6], ad_[6];
#pragma unroll
    for (int nt = 0; nt < 6; ++nt) {
        as_[nt] = att_src[nt * 16 + lo16];
        ad_[nt] = att_dst[nt * 16 + lo16];
    }
    bool lo8 = lo16 < 8;
    float a1lo = lo8 ? as_[1] : 0.f, a1hi = lo8 ? 0.f : as_[1];
    float d1lo = lo8 ? ad_[1] : 0.f, d1hi = lo8 ? 0.f : ad_[1];
    float a4lo = lo8 ? as_[4] : 0.f, a4hi = lo8 ? 0.f : as_[4];
    float d4lo = lo8 ? ad_[4] : 0.f, d4hi = lo8 ? 0.f : ad_[4];

    float sA[4][4], sD[4][4];
#pragma unroll
    for (int i = 0; i < 4; ++i) {
        float v0 = c[0][i], v1 = c[1][i], v2 = c[2][i];
        float v3 = c[3][i], v4 = c[4][i], v5 = c[5][i];
        sA[i][0] = v0 * as_[0] + v1 * a1lo;
        sA[i][1] = v1 * a1hi + v2 * as_[2];
        sA[i][2] = v3 * as_[3] + v4 * a4lo;
        sA[i][3] = v4 * a4hi + v5 * as_[5];
        sD[i][0] = v0 * ad_[0] + v1 * d1lo;
        sD[i][1] = v1 * d1hi + v2 * ad_[2];
        sD[i][2] = v3 * ad_[3] + v4 * d4lo;
        sD[i][3] = v4 * d4hi + v5 * ad_[5];
    }
#pragma unroll
    for (int i = 0; i < 4; ++i)
#pragma unroll
        for (int h = 0; h < 4; ++h) {
#pragma unroll
            for (int m = 1; m < 16; m <<= 1) {
                sA[i][h] += __shfl_xor(sA[i][h], m);
                sD[i][h] += __shfl_xor(sD[i][h], m);
            }
        }
    {
        int rr = row0 + grp * 4 + lo16;
        if (lo16 < 4 && rr < n) {
            float4 pv, dv;
            if (lo16 == 0) {
                pv = make_float4(sA[0][0], sA[0][1], sA[0][2], sA[0][3]);
                dv = make_float4(sD[0][0], sD[0][1], sD[0][2], sD[0][3]);
            } else if (lo16 == 1) {
                pv = make_float4(sA[1][0], sA[1][1], sA[1][2], sA[1][3]);
                dv = make_float4(sD[1][0], sD[1][1], sD[1][2], sD[1][3]);
            } else if (lo16 == 2) {
                pv = make_float4(sA[2][0], sA[2][1], sA[2][2], sA[2][3]);
                dv = make_float4(sD[2][0], sD[2][1], sD[2][2], sD[2][3]);
            } else {
                pv = make_float4(sA[3][0], sA[3][1], sA[3][2], sA[3][3]);
                dv = make_float4(sD[3][0], sD[3][1], sD[3][2], sD[3][3]);
            }
            ps[rr] = pv;
            *reinterpret_cast<float4*>(pdi + (size_t)rr * 8) = dv;
        }
    }
}

// ------------------------------------------------------------------
__device__ __forceinline__ float4 ev4(float4 a, float4 b, float4 c) {
    float l0 = a.x + b.x + c.x, l1 = a.y + b.y + c.y;
    float l2 = a.z + b.z + c.z, l3 = a.w + b.w + c.w;
    l0 = l0 >= 0.f ? l0 : 0.2f * l0;
    l1 = l1 >= 0.f ? l1 : 0.2f * l1;
    l2 = l2 >= 0.f ? l2 : 0.2f * l2;
    l3 = l3 >= 0.f ? l3 : 0.2f * l3;
    return make_float4(__expf(l0), __expf(l1), __expf(l2), __expf(l3));
}

__device__ __forceinline__ float gelu_f(float v) {
    float u = 0.7978845608028654f * (v + 0.044715f * v * v * v);
    u = fminf(fmaxf(u, -15.f), 15.f);
    float t = __expf(2.f * u);
    return 0.5f * v * (1.f + (t - 1.f) / (t + 1.f));
}

// ------------------------------------------------------------------
// Stage 2: one block per bin. Counting-sort by dlocal, compute ev, emit
// 16B CSR payload. ps gathers issued in pass 1; single-wave shfl scan.
__global__ __launch_bounds__(256) void bin_sort(
    const int* __restrict__ bincnt, const int2* __restrict__ binwords,
    const float4* __restrict__ ps, const float* __restrict__ pdi,
    const float4* __restrict__ prg,
    int4* __restrict__ csr, int* __restrict__ noff, int* __restrict__ ncnt,
    int n, int R_) {
    __shared__ int cnts[BINSZ];
    __shared__ int scanb[BINSZ];
    __shared__ int nbase[BINSZ];
    __shared__ float4 pdl[BINSZ];
    __shared__ float4 prl[RMAX];
    int bin = blockIdx.x;
    int node0 = bin * BINSZ;
    int total = min(bincnt[bin], BINCAP);

    for (int i = threadIdx.x; i < BINSZ; i += 256) {
        cnts[i] = 0;
        int nd = node0 + i;
        pdl[i] = (nd < n) ? *reinterpret_cast<const float4*>(pdi + (size_t)nd * 8)
                          : make_float4(0.f, 0.f, 0.f, 0.f);
    }
    for (int i = threadIdx.x; i < R_; i += 256) prl[i] = prg[i];
    __syncthreads();

    // pass 1: load records, ISSUE ps gathers, per-node rank via LDS atomic
    int2 w[6];
    int rk[6];
    float4 psv[6];
#pragma unroll
    for (int u = 0; u < 6; ++u) {
        int k = u * 256 + threadIdx.x;
        rk[u] = -1;
        if (k < total) {
            w[u] = binwords[(size_t)bin * BINCAP + k];
            psv[u] = ps[w[u].x & SRCM];
            int dl = (w[u].x >> (SRCB + ETB)) & (BINSZ - 1);
            rk[u] = atomicAdd(&cnts[dl], 1);
        }
    }
    __syncthreads();

    // single-wave inclusive scan of PADDED counts -> scanb
    if (threadIdx.x < 64) {
        int v = (cnts[threadIdx.x] + 3) & ~3;
#pragma unroll
        for (int s = 1; s < 64; s <<= 1) {
            int t = __shfl_up(v, s, 64);
            if ((int)threadIdx.x >= s) v += t;
        }
        scanb[threadIdx.x] = v;
    }
    __syncthreads();
    if (threadIdx.x < BINSZ) {
        int cnt = cnts[threadIdx.x];
        int cntP = (cnt + 3) & ~3;
        int nb = scanb[threadIdx.x] - cntP;
        nbase[threadIdx.x] = nb;
        int nd = node0 + threadIdx.x;
        if (nd < n) {
            noff[nd] = bin * BINCAP + nb;
            ncnt[nd] = cnt;
        }
        // zero-fill pad entries (<=3 per node)
        int4 z = make_int4(0, 0, 0, 0);
        for (int i = cnt; i < cntP; ++i)
            csr[(size_t)bin * BINCAP + nb + i] = z;
    }
    // zero 12 entries past the bin's padded grand total (over-read window)
    {
        int gt = scanb[BINSZ - 1];
        if (threadIdx.x < 12) {
            int p = gt + threadIdx.x;
            if (p < BINCAP)
                csr[(size_t)bin * BINCAP + p] = make_int4(0, 0, 0, 0);
        }
    }
    __syncthreads();

    // pass 2: compute ev, write CSR payload sequentially per node
#pragma unroll
    for (int u = 0; u < 6; ++u) {
        if (rk[u] >= 0) {
            int s = w[u].x & SRCM;
            int t = (w[u].x >> SRCB) & ((1 << ETB) - 1);
            int dl = (w[u].x >> (SRCB + ETB)) & (BINSZ - 1);
            unsigned e = (unsigned)w[u].y;   // < 2^20
            float4 v = ev4(psv[u], pdl[dl], prl[t]);
            int4 pk;
            pk.x = (int)((unsigned)(s * (HIDC * 2)) | ((e & 0xFFu) << 24));
            pk.y = (int)((unsigned)(t * (HIDC * 2)) | ((e >> 8) << 13));
            pk.z = (int)h22u(__floats2half2_rn(v.x, v.y));
            pk.w = (int)h22u(__floats2half2_rn(v.z, v.w));
            csr[(size_t)bin * BINCAP + nbase[dl] + rk[u]] = pk;
        }
    }
}

// ------------------------------------------------------------------
// node_agg + fused alpha: R3-form main loop (best of seven variants),
// then a second pass over the node's CSR segment writes
// alpha[e] = ev * inv using the packed edge id.
__global__ __launch_bounds__(256) void node_agg(
    const __half* __restrict__ h16, const float* __restrict__ rel,
    const int4* __restrict__ csr, const int* __restrict__ noff,
    const int* __restrict__ ncnt,
    const float* __restrict__ bias,
    float* __restrict__ out, float4* __restrict__ alpha, int n, int R_) {
    __shared__ uint2 relh[RMAX * HIDC / 4];   // rel as fp16, 7.7 KB
    for (int i = threadIdx.x; i < R_ * 24; i += 256) {
        float4 v = reinterpret_cast<const float4*>(rel)[i];
        uint2 pk;
        pk.x = h22u(__floats2half2_rn(v.x, v.y));
        pk.y = h22u(__floats2half2_rn(v.z, v.w));
        relh[i] = pk;
    }
    __syncthreads();

    int lane = threadIdx.x & 31;
    if (lane >= 24) return;
    const int j = lane;
    const int j4 = 4 * j;
    const int hh = j / 6;
    const unsigned joff = (unsigned)(j << 3);   // byte offset within a 192 B row
    const float4 bv = *reinterpret_cast<const float4*>(bias + j4);
    const char* h16c = reinterpret_cast<const char*>(h16);
    const char* relc = reinterpret_cast<const char*>(relh);
    const unsigned esel = (unsigned)(2 * hh) | ((unsigned)(2 * hh + 1) << 8);

    int hw0 = (blockIdx.x * blockDim.x + threadIdx.x) >> 5;
    int nHW = (gridDim.x * blockDim.x) >> 5;

    for (int hw = hw0; hw < n; hw += nHW) {
        int cnt = ncnt[hw];
        const int4* sp0 = csr + noff[hw];
        const int4* sp = sp0;
        float a0 = 0.f, a1 = 0.f, a2 = 0.f, a3 = 0.f;
        float dsum = 0.f;

        if (cnt > 0) {
            int cntP = (cnt + 3) & ~3;   // segment is zero-padded to this
            int4 pc[4];
#pragma unroll
            for (int u = 0; u < 4; ++u) pc[u] = sp[u];
            sp += 4;

            for (int k = 0; k < cntP; k += 4, sp += 4) {
                uint2 hv[4], rv[4];
#pragma unroll
                for (int u = 0; u < 4; ++u)
                    hv[u] = *reinterpret_cast<const uint2*>(
                        h16c + ((unsigned)pc[u].x & 0x00FFFFFFu) + joff);
#pragma unroll
                for (int u = 0; u < 4; ++u)
                    rv[u] = *reinterpret_cast<const uint2*>(
                        relc + ((unsigned)pc[u].y & 0x1FFFu) + joff);
                int4 pn[4];
#pragma unroll
                for (int u = 0; u < 4; ++u) pn[u] = sp[u];
#pragma unroll
                for (int u = 0; u < 4; ++u) {
                    unsigned e32 = __builtin_amdgcn_perm(
                        (unsigned)pc[u].w, (unsigned)pc[u].z, esel);
                    dsum += __half2float(__low2half(u2h2(e32)));
                    unsigned s01 = h22u(__hadd2(u2h2(hv[u].x), u2h2(rv[u].x)));
                    unsigned s23 = h22u(__hadd2(u2h2(hv[u].y), u2h2(rv[u].y)));
                    asm("v_fma_mix_f32 %0, %1, %2, %0 op_sel:[0,0,0] op_sel_hi:[1,1,0]"
                        : "+v"(a0) : "v"(s01), "v"(e32));
                    asm("v_fma_mix_f32 %0, %1, %2, %0 op_sel:[1,0,0] op_sel_hi:[1,1,0]"
                        : "+v"(a1) : "v"(s01), "v"(e32));
                    asm("v_fma_mix_f32 %0, %1, %2, %0 op_sel:[0,0,0] op_sel_hi:[1,1,0]"
                        : "+v"(a2) : "v"(s23), "v"(e32));
                    asm("v_fma_mix_f32 %0, %1, %2, %0 op_sel:[1,0,0] op_sel_hi:[1,1,0]"
                        : "+v"(a3) : "v"(s23), "v"(e32));
                }
#pragma unroll
                for (int u = 0; u < 4; ++u) pc[u] = pn[u];
            }
        }
        float inv = dsum > 0.f ? 1.f / dsum : 0.f;
        float4 o;
        o.x = gelu_f(a0 * inv + bv.x);
        o.y = gelu_f(a1 * inv + bv.y);
        o.z = gelu_f(a2 * inv + bv.z);
        o.w = gelu_f(a3 * inv + bv.w);
        *reinterpret_cast<float4*>(out + (size_t)hw * HIDC + j4) = o;

        // fused alpha: inv for all 4 heads via intra-half shuffles, then
        // each lane handles edges j, j+24, ... (exact cnt bound: pads and
        // over-read window never produce writes).
        if (cnt > 0) {
            float iv0 = __shfl(inv, 0, 32);
            float iv1 = __shfl(inv, 6, 32);
            float iv2 = __shfl(inv, 12, 32);
            float iv3 = __shfl(inv, 18, 32);
            for (int k = j; k < cnt; k += 24) {
                int4 pk = sp0[k];
                unsigned e_id = ((unsigned)pk.x >> 24) | (((unsigned)pk.y >> 13) << 8);
                float2 f01 = __half22float2(u2h2((unsigned)pk.z));
                float2 f23 = __half22float2(u2h2((unsigned)pk.w));
                alpha[e_id] = make_float4(f01.x * iv0, f01.y * iv1,
                                          f23.x * iv2, f23.y * iv3);
            }
        }
    }
}

// ------------------------------------------------------------------
extern "C" void kernel_launch(void* const* d_in, const int* in_sizes, int n_in,
                              void* d_out, int out_size, void* d_ws, size_t ws_size,
                              hipStream_t stream) {
    const float* x       = (const float*)d_in[0];
    const int*   eidx    = (const int*)d_in[1];
    const int*   etype   = (const int*)d_in[2];
    const float* W       = (const float*)d_in[3];
    const float* rel     = (const float*)d_in[4];
    const float* att_src = (const float*)d_in[5];
    const float* att_dst = (const float*)d_in[6];
    const float* att_rel = (const float*)d_in[7];
    const float* bias    = (const float*)d_in[8];

    int N_ = in_sizes[0] / HIDC;
    int E_ = in_sizes[1] / 2;
    int R_ = in_sizes[4] / HIDC;
    const int* src  = eidx;
    const int* dstp = eidx + E_;
    int nbins = (N_ + BINSZ - 1) / BINSZ;

    // workspace layout (16B-aligned chunks), ~38 MB total
    char* ws = (char*)d_ws;
    __half* h16      = (__half*)ws; ws += (size_t)N_ * HIDC * 2;        // 9.6 MB
    float4* ps       = (float4*)ws; ws += (size_t)N_ * 16;              // 0.8 MB
    float*  pdi      = (float*)ws;  ws += (size_t)N_ * 32;              // 1.6 MB (pd | spare)
    float4* pr       = (float4*)ws; ws += 1024;
    int*    bincnt   = (int*)ws;    ws += (size_t)((nbins + 3) & ~3) * 4;
    int*    noff     = (int*)ws;    ws += (size_t)((N_ + 3) & ~3) * 4;  // 0.2 MB
    int*    ncnt     = (int*)ws;    ws += (size_t)((N_ + 3) & ~3) * 4;  // 0.2 MB
    int2*   binwords = (int2*)ws;   ws += (size_t)nbins * BINCAP * 8;   // 8.4 MB
    int4*   csr      = (int4*)ws;   ws += (size_t)nbins * BINCAP * 16 + 256; // 16.8 MB (+slack)

    float*  outv  = (float*)d_out;                       // N*96
    float4* alpha = (float4*)(outv + (size_t)N_ * HIDC); // E*4

    int gemmBlocks = (N_ + 63) / 64;
    int edgeBlocks = (E_ + TILE - 1) / TILE;

    // pre-zero bin counters + csr tail slack (graph-capture-safe memsets)
    hipMemsetAsync(bincnt, 0, (size_t)nbins * 4, stream);
    hipMemsetAsync(csr + (size_t)nbins * BINCAP, 0, 16 * sizeof(int4), stream);

    gemm_bin<<<gemmBlocks + edgeBlocks, 256, 0, stream>>>(
        x, W, att_src, att_dst, rel, att_rel, h16, ps, pdi, pr,
        src, dstp, etype, bincnt, binwords, N_, nbins, R_, E_, gemmBlocks);

    bin_sort<<<nbins, 256, 0, stream>>>(
        bincnt, binwords, ps, pdi, pr, csr, noff, ncnt, N_, R_);

    node_agg<<<(N_ + 15) / 16, 256, 0, stream>>>(
        h16, rel, csr, noff, ncnt, bias, outv, alpha, N_, R_);
}